// Round 14
// baseline (198.957 us; speedup 1.0000x reference)
//
#include <hip/hip_runtime.h>
#include <hip/hip_bf16.h>
#include <math.h>

#define NEG_SLOPE 0.2f
typedef unsigned short u16;
typedef short bf16x8 __attribute__((ext_vector_type(8)));
typedef float f32x4 __attribute__((ext_vector_type(4)));

__device__ __forceinline__ float bfu2f(u16 u) { return __uint_as_float(((unsigned)u) << 16); }
__device__ __forceinline__ u16 f2bu(float v) { return __bfloat16_as_ushort(__float2bfloat16(v)); }

__device__ __forceinline__ void gload_lds16(const void* g, void* l) {
    __builtin_amdgcn_global_load_lds((const __attribute__((address_space(1))) void*)g,
                                     (__attribute__((address_space(3))) void*)l, 16, 0, 0);
}

// ---------------- prep: init + LDS-tiled W transposes + ws/wd precompute ----------------
// block ranges: [0,c0) init deg/cursor; [c0,c0+70) 64x64 tile transposes
// (W1:2, W2:4, W3:64); [c0+70, c0+70+80) ws/wd dot products.
__global__ void prep_kernel(int* deg, int* cursor, int N,
                            const float* __restrict__ W1, u16* __restrict__ Wt1,
                            const float* __restrict__ W2, u16* __restrict__ Wt2,
                            const float* __restrict__ W3, u16* __restrict__ Wt3,
                            const float* __restrict__ as2, const float* __restrict__ ad2,
                            const float* __restrict__ as3, const float* __restrict__ ad3,
                            float* __restrict__ ws2, float* __restrict__ wd2,
                            float* __restrict__ ws3, float* __restrict__ wd3,
                            int c0) {
    __shared__ u16 sm[64][66];
    int bid = blockIdx.x, tid = threadIdx.x;
    if (bid < c0) {
        int i = bid * 256 + tid;
        if (i < N) { deg[i] = 0; cursor[i] = 0; }
    } else if (bid < c0 + 70) {
        int tb = bid - c0;
        const float* W; u16* Wt; int K, F, kt, ft;
        if (tb < 2)      { W = W1; Wt = Wt1; K = 128; F = 64;   kt = tb;          ft = 0; }
        else if (tb < 6) { W = W2; Wt = Wt2; K = 64;  F = 256;  kt = 0;           ft = tb - 2; }
        else             { W = W3; Wt = Wt3; K = 256; F = 1024; kt = (tb - 6) & 3; ft = (tb - 6) >> 2; }
        int ty = tid >> 6, tx = tid & 63;
#pragma unroll
        for (int r = 0; r < 16; ++r) {
            int kl = r * 4 + ty;
            sm[kl][tx] = f2bu(W[(size_t)(kt * 64 + kl) * F + ft * 64 + tx]);
        }
        __syncthreads();
#pragma unroll
        for (int r = 0; r < 16; ++r) {
            int fl = r * 4 + ty;
            Wt[(size_t)(ft * 64 + fl) * K + kt * 64 + tx] = sm[tx][fl];
        }
    } else {
        int wv = ((bid - c0 - 70) * 256 + tid) >> 6;   // 0..319
        int lane = tid & 63;
        const float *W, *va, *vd; float *os, *od; int F, row;
        if (wv < 64) { W = W2; va = as2; vd = ad2; F = 256; row = wv; os = ws2; od = wd2; }
        else if (wv < 320) { W = W3; va = as3; vd = ad3; F = 1024; row = wv - 64; os = ws3; od = wd3; }
        else return;
        const float* wr = W + (size_t)row * F;
        float ss = 0.f, dd = 0.f;
        for (int f = lane; f < F; f += 64) { float wvv = wr[f]; ss += wvv * va[f]; dd += wvv * vd[f]; }
        for (int off = 32; off; off >>= 1) { ss += __shfl_xor(ss, off); dd += __shfl_xor(dd, off); }
        if (lane == 0) { os[row] = ss; od[row] = dd; }
    }
}

// ---------------- CSR build ----------------
__global__ void count_kernel(const int* __restrict__ edst, int E, int N, int* deg) {
    int i = blockIdx.x * blockDim.x + threadIdx.x;
    int total = E + N;
    if (i >= total) return;
    int dn = (i < E) ? edst[i] : (i - E);
    atomicAdd(&deg[dn], 1);
}

__global__ void scan_kernel(const int* __restrict__ deg, int N, int* __restrict__ offsets) {
    __shared__ int part[257];
    int tid = threadIdx.x;
    int chunk = (N + 255) / 256;
    int begin = tid * chunk;
    int fin = begin + chunk; if (fin > N) fin = N; if (begin > N) begin = N;
    int sum = 0;
    for (int i = begin; i < fin; ++i) sum += deg[i];
    part[tid] = sum;
    __syncthreads();
    if (tid == 0) {
        int acc = 0;
        for (int t = 0; t < 256; ++t) { int v = part[t]; part[t] = acc; acc += v; }
        part[256] = acc;
    }
    __syncthreads();
    int acc = part[tid];
    for (int i = begin; i < fin; ++i) { offsets[i] = acc; acc += deg[i]; }
    if (tid == 255) offsets[N] = part[256];
}

__global__ void scatter_kernel(const int* __restrict__ esrc, const int* __restrict__ edst,
                               int E, int N, const int* __restrict__ offsets,
                               int* cursor, int* __restrict__ srcg) {
    int i = blockIdx.x * blockDim.x + threadIdx.x;
    int total = E + N;
    if (i >= total) return;
    int sn, dn;
    if (i < E) { sn = esrc[i]; dn = edst[i]; } else { sn = i - E; dn = i - E; }
    int pos = atomicAdd(&cursor[dn], 1);
    srcg[offsets[dn] + pos] = sn;
}

// ---------------- gemm1: f32 A input, bf16 fragments in-register; K=128, F=64, SD epilogue ----------------
__global__ __launch_bounds__(256) void gemm1_kernel(const float* __restrict__ X,
                                                    const u16* __restrict__ Wt,
                                                    u16* __restrict__ C,
                                                    int M,
                                                    const float* __restrict__ asv,
                                                    const float* __restrict__ adv,
                                                    float* __restrict__ s_out,
                                                    float* __restrict__ d_out) {
    constexpr int K = 128, NK = 4;
    int tid = threadIdx.x;
    int w = tid >> 6, l = tid & 63;
    int l15 = l & 15, q = l >> 4;
    int bm = blockIdx.x * 64;
    int row = bm + w * 16 + l15;
    int arow = (row < M) ? row : (M - 1);
    const float* aptr = X + (size_t)arow * K + 8 * q;
    const u16* bptr[4];
#pragma unroll
    for (int nt = 0; nt < 4; ++nt)
        bptr[nt] = Wt + (size_t)(nt * 16 + l15) * K + 8 * q;

    f32x4 acc[4];
#pragma unroll
    for (int nt = 0; nt < 4; ++nt) acc[nt] = (f32x4){0.f, 0.f, 0.f, 0.f};

    float4 a0_cur = *(const float4*)(aptr);
    float4 a1_cur = *(const float4*)(aptr + 4);
    bf16x8 b_cur[4], b_nxt[4];
    float4 a0_nxt, a1_nxt;
#pragma unroll
    for (int nt = 0; nt < 4; ++nt) b_cur[nt] = *(const bf16x8*)(bptr[nt]);

#pragma unroll
    for (int kk = 0; kk < NK; ++kk) {
        if (kk + 1 < NK) {
            int koff = (kk + 1) * 32;
            a0_nxt = *(const float4*)(aptr + koff);
            a1_nxt = *(const float4*)(aptr + koff + 4);
#pragma unroll
            for (int nt = 0; nt < 4; ++nt) b_nxt[nt] = *(const bf16x8*)(bptr[nt] + koff);
        }
        bf16x8 a8;
        u16* ap = (u16*)&a8;
        ap[0] = f2bu(a0_cur.x); ap[1] = f2bu(a0_cur.y); ap[2] = f2bu(a0_cur.z); ap[3] = f2bu(a0_cur.w);
        ap[4] = f2bu(a1_cur.x); ap[5] = f2bu(a1_cur.y); ap[6] = f2bu(a1_cur.z); ap[7] = f2bu(a1_cur.w);
#pragma unroll
        for (int nt = 0; nt < 4; ++nt)
            acc[nt] = __builtin_amdgcn_mfma_f32_16x16x32_bf16(b_cur[nt], a8, acc[nt], 0, 0, 0);
        if (kk + 1 < NK) {
            a0_cur = a0_nxt; a1_cur = a1_nxt;
#pragma unroll
            for (int nt = 0; nt < 4; ++nt) b_cur[nt] = b_nxt[nt];
        }
    }

    if (row < M) {
#pragma unroll
        for (int nt = 0; nt < 4; ++nt) {
            int col = nt * 16 + 4 * q;
            ushort4 st;
#pragma unroll
            for (int r = 0; r < 4; ++r) ((u16*)&st)[r] = f2bu(acc[nt][r]);
            *(ushort4*)(C + (size_t)row * 64 + col) = st;
        }
    }
    // SD epilogue: full row across q-lanes
    float ss = 0.f, dd = 0.f;
#pragma unroll
    for (int nt = 0; nt < 4; ++nt)
#pragma unroll
        for (int r = 0; r < 4; ++r) {
            int col = nt * 16 + 4 * q + r;
            float v = acc[nt][r];
            ss += v * asv[col];
            dd += v * adv[col];
        }
    ss += __shfl_xor(ss, 16); ss += __shfl_xor(ss, 32);
    dd += __shfl_xor(dd, 16); dd += __shfl_xor(dd, 32);
    if (q == 0 && row < M) { s_out[row] = ss; d_out[row] = dd; }
}

// ---------------- register-direct MFMA GEMM (layer 2) ----------------
template <int K, int MR, bool BIASRELU>
__global__ __launch_bounds__(256) void mfma_gemm(const u16* __restrict__ A,
                                                 const u16* __restrict__ Wt,
                                                 u16* __restrict__ C,
                                                 const float* __restrict__ bias,
                                                 int M, int F) {
    constexpr int NK = K / 32;
    int tid = threadIdx.x;
    int w = tid >> 6, l = tid & 63;
    int l15 = l & 15, q = l >> 4;
    int bm = blockIdx.x * (64 * MR);
    int bn = blockIdx.y * 64;
    int r0 = bm + w * (16 * MR);

    const u16* aptr[MR];
    int row[MR];
#pragma unroll
    for (int mr = 0; mr < MR; ++mr) {
        int r = r0 + mr * 16 + l15;
        row[mr] = r;
        int ar = (r < M) ? r : (M - 1);
        aptr[mr] = A + (size_t)ar * K + 8 * q;
    }
    const u16* bptr[4];
#pragma unroll
    for (int nt = 0; nt < 4; ++nt)
        bptr[nt] = Wt + (size_t)(bn + nt * 16 + l15) * K + 8 * q;

    f32x4 acc[MR][4];
#pragma unroll
    for (int mr = 0; mr < MR; ++mr)
#pragma unroll
        for (int nt = 0; nt < 4; ++nt) acc[mr][nt] = (f32x4){0.f, 0.f, 0.f, 0.f};

    bf16x8 a_cur[MR], b_cur[4], a_nxt[MR], b_nxt[4];
#pragma unroll
    for (int mr = 0; mr < MR; ++mr) a_cur[mr] = *(const bf16x8*)(aptr[mr]);
#pragma unroll
    for (int nt = 0; nt < 4; ++nt) b_cur[nt] = *(const bf16x8*)(bptr[nt]);

#pragma unroll
    for (int kk = 0; kk < NK; ++kk) {
        if (kk + 1 < NK) {
            int koff = (kk + 1) * 32;
#pragma unroll
            for (int mr = 0; mr < MR; ++mr) a_nxt[mr] = *(const bf16x8*)(aptr[mr] + koff);
#pragma unroll
            for (int nt = 0; nt < 4; ++nt) b_nxt[nt] = *(const bf16x8*)(bptr[nt] + koff);
        }
#pragma unroll
        for (int mr = 0; mr < MR; ++mr)
#pragma unroll
            for (int nt = 0; nt < 4; ++nt)
                acc[mr][nt] = __builtin_amdgcn_mfma_f32_16x16x32_bf16(b_cur[nt], a_cur[mr], acc[mr][nt], 0, 0, 0);
        if (kk + 1 < NK) {
#pragma unroll
            for (int mr = 0; mr < MR; ++mr) a_cur[mr] = a_nxt[mr];
#pragma unroll
            for (int nt = 0; nt < 4; ++nt) b_cur[nt] = b_nxt[nt];
        }
    }

#pragma unroll
    for (int mr = 0; mr < MR; ++mr) {
        if (row[mr] >= M) continue;
#pragma unroll
        for (int nt = 0; nt < 4; ++nt) {
            int col = bn + nt * 16 + 4 * q;
            ushort4 st;
#pragma unroll
            for (int r = 0; r < 4; ++r) {
                float v = acc[mr][nt][r];
                if (BIASRELU) { v += bias[col + r]; v = fmaxf(v, 0.f); }
                ((u16*)&st)[r] = f2bu(v);
            }
            *(ushort4*)(C + (size_t)row[mr] * F + col) = st;
        }
    }
}

// ---------------- gemm3: one-shot LDS A + cb-pair loop (B restaged), pool partials ----------------
__global__ __launch_bounds__(512) void gemm3_kernel(const u16* __restrict__ A,
                                                    const u16* __restrict__ Wt,
                                                    const float* __restrict__ bias,
                                                    int M,
                                                    float* __restrict__ pmaxbuf) {
    constexpr int K = 256;
    constexpr int ABYTES = 128 * 512;        // 64 KB
    __shared__ char lds[2 * ABYTES];         // A + B = 128 KB
    int tid = threadIdx.x;
    int w = tid >> 6, lane = tid & 63;
    int w2 = w >> 2, wc = w & 3;             // row-half, col-quarter
    int l15 = lane & 15, q = lane >> 4;
    int bid = blockIdx.x;
    int rb = bid >> 2, cbp = bid & 3;
    int bm = rb * 128;

    // stage A once: 4096 x 16B chunks, swizzled global source
#pragma unroll
    for (int it = 0; it < 8; ++it) {
        int c = it * 512 + tid;
        int row = c >> 5, kc = c & 31;
        int arow = bm + row; if (arow >= M) arow = M - 1;
        gload_lds16(A + (size_t)arow * K + ((kc ^ (row & 7)) * 8),
                    lds + (size_t)(it * 512 + (tid & ~63)) * 16);
    }

    const char* abase = lds;
    char* bldst = lds + ABYTES;

    for (int half = 0; half < 2; ++half) {
        if (half) __syncthreads();           // all waves done reading previous B
        int bn = cbp * 256 + half * 128;
#pragma unroll
        for (int it = 0; it < 8; ++it) {
            int c = it * 512 + tid;
            int col = c >> 5, kc = c & 31;
            gload_lds16(Wt + (size_t)(bn + col) * K + ((kc ^ (col & 7)) * 8),
                        bldst + (size_t)(it * 512 + (tid & ~63)) * 16);
        }
        __syncthreads();

        f32x4 acc[4][2];
#pragma unroll
        for (int mr = 0; mr < 4; ++mr)
#pragma unroll
            for (int nt = 0; nt < 2; ++nt) acc[mr][nt] = (f32x4){0.f, 0.f, 0.f, 0.f};

        const char* bbase = bldst;
#pragma unroll
        for (int kk = 0; kk < 8; ++kk) {
            int c = kk * 4 + q;
            bf16x8 af[4], bfr[2];
#pragma unroll
            for (int mr = 0; mr < 4; ++mr) {
                int row = w2 * 64 + mr * 16 + l15;
                af[mr] = *(const bf16x8*)(abase + row * 512 + ((c ^ (row & 7)) * 16));
            }
#pragma unroll
            for (int nt = 0; nt < 2; ++nt) {
                int col = wc * 32 + nt * 16 + l15;
                bfr[nt] = *(const bf16x8*)(bbase + col * 512 + ((c ^ (col & 7)) * 16));
            }
#pragma unroll
            for (int mr = 0; mr < 4; ++mr)
#pragma unroll
                for (int nt = 0; nt < 2; ++nt)
                    acc[mr][nt] = __builtin_amdgcn_mfma_f32_16x16x32_bf16(bfr[nt], af[mr], acc[mr][nt], 0, 0, 0);
        }

        float pmax[2][4];
#pragma unroll
        for (int nt = 0; nt < 2; ++nt)
#pragma unroll
            for (int r = 0; r < 4; ++r) pmax[nt][r] = 0.f;
#pragma unroll
        for (int mr = 0; mr < 4; ++mr) {
            bool valid = (bm + w2 * 64 + mr * 16 + l15) < M;
#pragma unroll
            for (int nt = 0; nt < 2; ++nt)
#pragma unroll
                for (int r = 0; r < 4; ++r) {
                    float v = acc[mr][nt][r] + bias[bn + wc * 32 + nt * 16 + 4 * q + r];
                    v = fmaxf(v, 0.f);
                    if (valid) pmax[nt][r] = fmaxf(pmax[nt][r], v);
                }
        }
#pragma unroll
        for (int nt = 0; nt < 2; ++nt)
#pragma unroll
            for (int r = 0; r < 4; ++r) {
#pragma unroll
                for (int msk = 1; msk < 16; msk <<= 1)
                    pmax[nt][r] = fmaxf(pmax[nt][r], __shfl_xor(pmax[nt][r], msk));
            }
        if (l15 == 0) {
#pragma unroll
            for (int nt = 0; nt < 2; ++nt)
#pragma unroll
                for (int r = 0; r < 4; ++r)
                    pmaxbuf[(size_t)(rb * 2 + w2) * 1024 + bn + wc * 32 + nt * 16 + 4 * q + r] = pmax[nt][r];
        }
    }
}

// ---------------- standalone sd (layer 3: s,d from a2) ----------------
__global__ void sd_kernel(const u16* __restrict__ h, const float* __restrict__ a_s,
                          const float* __restrict__ a_d, int N, int F,
                          float* __restrict__ s, float* __restrict__ d) {
    int wave = (blockIdx.x * blockDim.x + threadIdx.x) >> 6;
    int lane = threadIdx.x & 63;
    if (wave >= N) return;
    const u16* hrow = h + (size_t)wave * F;
    float ss = 0.f, dd = 0.f;
    for (int f = lane * 4; f < F; f += 256) {
        ushort4 u = *reinterpret_cast<const ushort4*>(hrow + f);
        float4 av = *reinterpret_cast<const float4*>(a_s + f);
        float4 dv = *reinterpret_cast<const float4*>(a_d + f);
        float h0 = bfu2f(u.x), h1 = bfu2f(u.y), h2 = bfu2f(u.z), h3 = bfu2f(u.w);
        ss += h0 * av.x + h1 * av.y + h2 * av.z + h3 * av.w;
        dd += h0 * dv.x + h1 * dv.y + h2 * dv.z + h3 * dv.w;
    }
    for (int off = 32; off; off >>= 1) { ss += __shfl_xor(ss, off); dd += __shfl_xor(dd, off); }
    if (lane == 0) { s[wave] = ss; d[wave] = dd; }
}

// ---------------- alpha: normalized softmax weights per edge (wave-per-node, exp-once) ----------------
__global__ void alpha_kernel(const float* __restrict__ sv, const float* __restrict__ dvec,
                             const int* __restrict__ srcg, const int* __restrict__ offsets,
                             int N, float* __restrict__ ag) {
    int n = (blockIdx.x * blockDim.x + threadIdx.x) >> 6;
    int lane = threadIdx.x & 63;
    if (n >= N) return;
    int start = offsets[n], end = offsets[n + 1];
    float dval = dvec[n];
    if (end - start <= 64) {
        int j0 = start + lane;
        float e0 = -INFINITY;
        if (j0 < end) {
            float v = sv[srcg[j0]] + dval;
            e0 = (v >= 0.f) ? v : NEG_SLOPE * v;
        }
        float m = e0;
#pragma unroll
        for (int off = 32; off; off >>= 1) m = fmaxf(m, __shfl_xor(m, off));
        float p = (j0 < end) ? expf(e0 - m) : 0.f;
        float ls = p;
#pragma unroll
        for (int off = 32; off; off >>= 1) ls += __shfl_xor(ls, off);
        if (j0 < end) ag[j0] = p / ls;
    } else {
        float lmax = -INFINITY;
        for (int j = start + lane; j < end; j += 64) {
            float v = sv[srcg[j]] + dval; v = (v >= 0.f) ? v : NEG_SLOPE * v;
            lmax = fmaxf(lmax, v);
        }
#pragma unroll
        for (int off = 32; off; off >>= 1) lmax = fmaxf(lmax, __shfl_xor(lmax, off));
        float ls = 0.f;
        for (int j = start + lane; j < end; j += 64) {
            float v = sv[srcg[j]] + dval; v = (v >= 0.f) ? v : NEG_SLOPE * v;
            ls += expf(v - lmax);
        }
#pragma unroll
        for (int off = 32; off; off >>= 1) ls += __shfl_xor(ls, off);
        float inv = 1.f / ls;
        for (int j = start + lane; j < end; j += 64) {
            float v = sv[srcg[j]] + dval; v = (v >= 0.f) ? v : NEG_SLOPE * v;
            ag[j] = expf(v - lmax) * inv;
        }
    }
}

// ---------------- pure gather: LDS-staged ag/src, 8-edge unrolled, ushort2/lane ----------------
template <int F, int FS>   // F=256, FS=2 -> FB=128, VPT=2
__global__ __launch_bounds__(256) void gather_kernel(const u16* __restrict__ h,
                                                     const float* __restrict__ ag,
                                                     const int* __restrict__ srcg,
                                                     const int* __restrict__ offsets,
                                                     u16* __restrict__ out) {
    constexpr int FB = F / FS;
    constexpr int VPT = FB / 64;  // 2
    __shared__ float aL[256];
    __shared__ int sL[256];
    __shared__ float red[3][FB];
    int n = blockIdx.x;
    int f0 = blockIdx.y * FB;
    int tid = threadIdx.x, w = tid >> 6, lane = tid & 63;
    int start = offsets[n], end = offsets[n + 1];
    int deg = end - start;
    float acc0 = 0.f, acc1 = 0.f;

    for (int base = 0; base < deg; base += 256) {
        int cnt = deg - base; if (cnt > 256) cnt = 256;
        if (base) __syncthreads();
        if (tid < cnt) { aL[tid] = ag[start + base + tid]; sL[tid] = srcg[start + base + tid]; }
        __syncthreads();
        int j = w;
        for (; j + 28 < cnt; j += 32) {   // 8 independent edges per wave-step
            float a0 = aL[j],      a1 = aL[j + 4],  a2 = aL[j + 8],  a3 = aL[j + 12];
            float a4 = aL[j + 16], a5 = aL[j + 20], a6 = aL[j + 24], a7 = aL[j + 28];
            ushort2 u0 = *(const ushort2*)(h + (size_t)sL[j] * F + f0 + lane * VPT);
            ushort2 u1 = *(const ushort2*)(h + (size_t)sL[j + 4] * F + f0 + lane * VPT);
            ushort2 u2 = *(const ushort2*)(h + (size_t)sL[j + 8] * F + f0 + lane * VPT);
            ushort2 u3 = *(const ushort2*)(h + (size_t)sL[j + 12] * F + f0 + lane * VPT);
            ushort2 u4 = *(const ushort2*)(h + (size_t)sL[j + 16] * F + f0 + lane * VPT);
            ushort2 u5 = *(const ushort2*)(h + (size_t)sL[j + 20] * F + f0 + lane * VPT);
            ushort2 u6 = *(const ushort2*)(h + (size_t)sL[j + 24] * F + f0 + lane * VPT);
            ushort2 u7 = *(const ushort2*)(h + (size_t)sL[j + 28] * F + f0 + lane * VPT);
            acc0 += a0 * bfu2f(u0.x) + a1 * bfu2f(u1.x) + a2 * bfu2f(u2.x) + a3 * bfu2f(u3.x)
                  + a4 * bfu2f(u4.x) + a5 * bfu2f(u5.x) + a6 * bfu2f(u6.x) + a7 * bfu2f(u7.x);
            acc1 += a0 * bfu2f(u0.y) + a1 * bfu2f(u1.y) + a2 * bfu2f(u2.y) + a3 * bfu2f(u3.y)
                  + a4 * bfu2f(u4.y) + a5 * bfu2f(u5.y) + a6 * bfu2f(u6.y) + a7 * bfu2f(u7.y);
        }
        for (; j < cnt; j += 4) {
            float a = aL[j];
            ushort2 u = *(const ushort2*)(h + (size_t)sL[j] * F + f0 + lane * VPT);
            acc0 += a * bfu2f(u.x);
            acc1 += a * bfu2f(u.y);
        }
    }

    if (w > 0) { red[w - 1][lane * 2] = acc0; red[w - 1][lane * 2 + 1] = acc1; }
    __syncthreads();
    if (w != 0) return;
    ushort2 st;
    float x0 = acc0 + red[0][lane * 2] + red[1][lane * 2] + red[2][lane * 2];
    float x1 = acc1 + red[0][lane * 2 + 1] + red[1][lane * 2 + 1] + red[2][lane * 2 + 1];
    st.x = f2bu(x0); st.y = f2bu(x1);
    *(ushort2*)(out + (size_t)n * F + f0 + lane * 2) = st;
}

// ---------------- fused softmax + gather, exp-once LDS softmax (layers 1/2, F=64) ----------------
template <int F, bool BIASRELU, bool SD_EPI>
__global__ __launch_bounds__(256) void agg_kernel(const u16* __restrict__ h,
                                                  const float* __restrict__ sv,
                                                  const float* __restrict__ dvec,
                                                  const int* __restrict__ srcg,
                                                  const int* __restrict__ offsets,
                                                  const float* __restrict__ bias,
                                                  u16* __restrict__ out,
                                                  const float* __restrict__ wsv,
                                                  const float* __restrict__ wdv,
                                                  float* __restrict__ s_out,
                                                  float* __restrict__ d_out) {
    constexpr int VPT = F / 64;
    __shared__ float pL[256];
    __shared__ int sL[256];
    __shared__ float red[3][F];
    int n = blockIdx.x;
    int tid = threadIdx.x;
    int w = tid >> 6, lane = tid & 63;
    int start = offsets[n], end = offsets[n + 1];
    int deg = end - start;
    float dval = dvec[n];
    float acc[VPT];
#pragma unroll
    for (int v = 0; v < VPT; ++v) acc[v] = 0.f;
    float inv;

    auto gpoint = [&](int sn) { return h + (size_t)sn * F + lane * VPT; };
    auto accum = [&](float pw, const u16* hp) {
        if constexpr (VPT == 1) {
            acc[0] += pw * bfu2f(*hp);
        } else {
            ushort2 u = *(const ushort2*)hp;
            acc[0] += pw * bfu2f(u.x); acc[1] += pw * bfu2f(u.y);
        }
    };

    if (deg <= 256) {
        float e = -INFINITY;
        if (tid < deg) {
            int sn = srcg[start + tid];
            sL[tid] = sn;
            float v = sv[sn] + dval;
            e = (v >= 0.f) ? v : NEG_SLOPE * v;
        }
        pL[tid] = e;
        __syncthreads();
        float m = fmaxf(fmaxf(pL[lane], pL[lane + 64]), fmaxf(pL[lane + 128], pL[lane + 192]));
#pragma unroll
        for (int off2 = 32; off2; off2 >>= 1) m = fmaxf(m, __shfl_xor(m, off2));
        __syncthreads();
        float p = (tid < deg) ? expf(e - m) : 0.f;
        pL[tid] = p;
        __syncthreads();
        float t4 = (pL[lane] + pL[lane + 64]) + (pL[lane + 128] + pL[lane + 192]);
#pragma unroll
        for (int off2 = 32; off2; off2 >>= 1) t4 += __shfl_xor(t4, off2);
        inv = 1.f / t4;
        int jj = w;
        for (; jj + 28 < deg; jj += 32) {  // 8 independent edges
            accum(pL[jj], gpoint(sL[jj]));
            accum(pL[jj + 4], gpoint(sL[jj + 4]));
            accum(pL[jj + 8], gpoint(sL[jj + 8]));
            accum(pL[jj + 12], gpoint(sL[jj + 12]));
            accum(pL[jj + 16], gpoint(sL[jj + 16]));
            accum(pL[jj + 20], gpoint(sL[jj + 20]));
            accum(pL[jj + 24], gpoint(sL[jj + 24]));
            accum(pL[jj + 28], gpoint(sL[jj + 28]));
        }
        for (; jj < deg; jj += 4) accum(pL[jj], gpoint(sL[jj]));
    } else {
        float lmax = -INFINITY;
        for (int j = start + lane; j < end; j += 64) {
            float v = sv[srcg[j]] + dval; v = (v >= 0.f) ? v : NEG_SLOPE * v;
            lmax = fmaxf(lmax, v);
        }
#pragma unroll
        for (int off2 = 32; off2; off2 >>= 1) lmax = fmaxf(lmax, __shfl_xor(lmax, off2));
        float ls = 0.f;
        for (int j = start + lane; j < end; j += 64) {
            float v = sv[srcg[j]] + dval; v = (v >= 0.f) ? v : NEG_SLOPE * v;
            ls += expf(v - lmax);
        }
#pragma unroll
        for (int off2 = 32; off2; off2 >>= 1) ls += __shfl_xor(ls, off2);
        inv = 1.f / ls;
        for (int j = start + w; j < end; j += 4) {
            int sn = srcg[j];
            float e2 = sv[sn] + dval; e2 = (e2 >= 0.f) ? e2 : NEG_SLOPE * e2;
            accum(expf(e2 - lmax), gpoint(sn));
        }
    }

    if (w > 0) {
#pragma unroll
        for (int v = 0; v < VPT; ++v) red[w - 1][lane * VPT + v] = acc[v];
    }
    __syncthreads();
    if (w != 0) return;
    float res0 = 0.f;
    if constexpr (VPT == 1) {
        float xv = (acc[0] + red[0][lane] + red[1][lane] + red[2][lane]) * inv;
        if (BIASRELU) { xv += bias[lane]; xv = fmaxf(xv, 0.f); }
        res0 = xv;
        out[(size_t)n * F + lane] = f2bu(xv);
    } else {
        ushort2 st;
#pragma unroll
        for (int v = 0; v < VPT; ++v) {
            float xv = (acc[v] + red[0][lane * 2 + v] + red[1][lane * 2 + v] + red[2][lane * 2 + v]) * inv;
            if (BIASRELU) { xv += bias[lane * 2 + v]; xv = fmaxf(xv, 0.f); }
            ((u16*)&st)[v] = f2bu(xv);
        }
        *(ushort2*)(out + (size_t)n * F + lane * 2) = st;
    }
    if constexpr (SD_EPI) { // F==64
        float ss = res0 * wsv[lane], dd = res0 * wdv[lane];
        for (int off2 = 32; off2; off2 >>= 1) { ss += __shfl_xor(ss, off2); dd += __shfl_xor(dd, off2); }
        if (lane == 0) { s_out[n] = ss; d_out[n] = dd; }
    }
}

// ---------------- dense head (pool fused into head1a) ----------------
__global__ void head1ap_kernel(const float* __restrict__ pmaxbuf, int nslices,
                               const float* __restrict__ lw1, float* __restrict__ part) {
    __shared__ float pk[64];
    int tid = threadIdx.x;          // 128
    int k0 = blockIdx.y * 64;
    if (tid < 64) {
        float m = 0.f;
#pragma unroll 4
        for (int s = 0; s < nslices; ++s) m = fmaxf(m, pmaxbuf[(size_t)s * 1024 + k0 + tid]);
        pk[tid] = m;
    }
    __syncthreads();
    int j = blockIdx.x * 128 + tid;
    float acc = 0.f;
#pragma unroll 8
    for (int kk = 0; kk < 64; ++kk) acc += pk[kk] * lw1[(size_t)(k0 + kk) * 512 + j];
    part[blockIdx.y * 512 + j] = acc;
}

__global__ void head1bc_kernel(const float* __restrict__ part, const float* __restrict__ lb1,
                               const float* __restrict__ lw2, const float* __restrict__ lb2,
                               float* __restrict__ out) {
    __shared__ float zs[512];
    __shared__ float z2s[10];
    int tid = threadIdx.x; // 640 threads = 10 waves
    if (tid < 512) {
        float acc = lb1[tid];
#pragma unroll
        for (int t = 0; t < 16; ++t) acc += part[t * 512 + tid];
        zs[tid] = fmaxf(acc, 0.f);
    }
    __syncthreads();
    int w = tid >> 6, lane = tid & 63;
    if (w < 10) {
        float acc = 0.f;
#pragma unroll
        for (int kc = 0; kc < 8; ++kc) {
            int k = kc * 64 + lane;
            acc += zs[k] * lw2[k * 10 + w];
        }
        for (int off = 32; off; off >>= 1) acc += __shfl_xor(acc, off);
        if (lane == 0) z2s[w] = acc + lb2[w];
    }
    __syncthreads();
    if (tid == 0) {
        float m = z2s[0];
        for (int j = 1; j < 10; ++j) m = fmaxf(m, z2s[j]);
        float ssum = 0.f;
        for (int j = 0; j < 10; ++j) ssum += expf(z2s[j] - m);
        float lse = m + logf(ssum);
        for (int j = 0; j < 10; ++j) out[j] = z2s[j] - lse;
    }
}

extern "C" void kernel_launch(void* const* d_in, const int* in_sizes, int n_in,
                              void* d_out, int out_size, void* d_ws, size_t ws_size,
                              hipStream_t stream) {
    const float* x   = (const float*)d_in[0];
    const int* ei    = (const int*)d_in[1];
    const float* W1  = (const float*)d_in[3];
    const float* as1 = (const float*)d_in[4];
    const float* ad1 = (const float*)d_in[5];
    const float* b1  = (const float*)d_in[6];
    const float* W2  = (const float*)d_in[7];
    const float* as2 = (const float*)d_in[8];
    const float* ad2 = (const float*)d_in[9];
    const float* b2  = (const float*)d_in[10];
    const float* W3  = (const float*)d_in[11];
    const float* as3 = (const float*)d_in[12];
    const float* ad3 = (const float*)d_in[13];
    const float* b3  = (const float*)d_in[14];
    const float* lw1 = (const float*)d_in[15];
    const float* lb1 = (const float*)d_in[16];
    const float* lw2 = (const float*)d_in[17];
    const float* lb2 = (const float*)d_in[18];
    float* out = (float*)d_out;

    const int N = in_sizes[0] / 128;
    const int E = in_sizes[1] / 2;
    const int total = E + N;
    const int* esrc = ei;
    const int* edst = ei + E;

    // bump allocator on d_ws, 256B aligned
    char* base = (char*)d_ws;
    size_t off = 0;
    auto alloc = [&](size_t bytes) { void* p = base + off; off = (off + bytes + 255) & ~(size_t)255; return p; };
    u16* h1    = (u16*)alloc((size_t)N * 64 * 2);
    u16* a1    = (u16*)alloc((size_t)N * 64 * 2);
    u16* agg2b = (u16*)alloc((size_t)N * 64 * 2);
    u16* a2    = (u16*)alloc((size_t)N * 256 * 2);
    u16* agg3b = (u16*)alloc((size_t)N * 256 * 2);
    u16* Wt1   = (u16*)alloc(128 * 64 * 2);
    u16* Wt2   = (u16*)alloc(64 * 256 * 2);
    u16* Wt3   = (u16*)alloc(256 * 1024 * 2);
    float* ws2 = (float*)alloc(64 * 4);
    float* wd2 = (float*)alloc(64 * 4);
    float* ws3 = (float*)alloc(256 * 4);
    float* wd3 = (float*)alloc(256 * 4);
    float* sbuf = (float*)alloc((size_t)N * 4);
    float* dbuf = (float*)alloc((size_t)N * 4);
    float* ag   = (float*)alloc((size_t)total * 4);
    float* hpart  = (float*)alloc(16 * 512 * 4);
    int* deg     = (int*)alloc((size_t)N * 4);
    int* cursor  = (int*)alloc((size_t)N * 4);
    int* offsets = (int*)alloc((size_t)(N + 1) * 4);
    int* srcg    = (int*)alloc((size_t)total * 4);
    int nrb128g = (N + 127) / 128;
    float* pmaxbuf = (float*)alloc((size_t)nrb128g * 2 * 1024 * 4);

    const int TPB = 256;
    int gE = (total + TPB - 1) / TPB;
    int gW = (N + 3) / 4;
    int gR64 = (N + 63) / 64;
    int gR128 = (N + 127) / 128;

    // prep (init + tiled W transposes + ws)
    int c0 = (N + 255) / 256;
    int gP = c0 + 70 + 80;
    prep_kernel<<<gP, TPB, 0, stream>>>(deg, cursor, N,
                                        W1, Wt1, W2, Wt2, W3, Wt3,
                                        as2, ad2, as3, ad3, ws2, wd2, ws3, wd3, c0);

    // CSR build
    count_kernel<<<gE, TPB, 0, stream>>>(edst, E, N, deg);
    scan_kernel<<<1, TPB, 0, stream>>>(deg, N, offsets);
    scatter_kernel<<<gE, TPB, 0, stream>>>(esrc, edst, E, N, offsets, cursor, srcg);

    // ---- layer 1: gemm1 (f32 A, +s1,d1 epilogue), fused agg (+s2,d2 epilogue on a1) ----
    gemm1_kernel<<<gR64, TPB, 0, stream>>>(x, Wt1, h1, N, as1, ad1, sbuf, dbuf);
    agg_kernel<64, true, true><<<N, TPB, 0, stream>>>(
        h1, sbuf, dbuf, srcg, offsets, b1, a1, ws2, wd2, sbuf, dbuf);

    // ---- layer 2: fused agg on a1 -> gemm2 (bias+relu) -> a2 ----
    agg_kernel<64, false, false><<<N, TPB, 0, stream>>>(
        a1, sbuf, dbuf, srcg, offsets, nullptr, agg2b, nullptr, nullptr, nullptr, nullptr);
    mfma_gemm<64, 2, true><<<dim3(gR128, 4), TPB, 0, stream>>>(
        agg2b, Wt2, a2, b2, N, 256);

    // ---- layer 3: sd3 -> alpha (exp-once) -> staged gather (f-split x2) -> gemm3 ----
    sd_kernel<<<gW, TPB, 0, stream>>>(a2, ws3, wd3, N, 256, sbuf, dbuf);
    alpha_kernel<<<gW, TPB, 0, stream>>>(sbuf, dbuf, srcg, offsets, N, ag);
    gather_kernel<256, 2><<<dim3(N, 2), TPB, 0, stream>>>(a2, ag, srcg, offsets, agg3b);
    gemm3_kernel<<<nrb128g * 4, 512, 0, stream>>>(agg3b, Wt3, b3, N, pmaxbuf);

    // ---- head (pool fused into head1ap) ----
    head1ap_kernel<<<dim3(4, 16), 128, 0, stream>>>(pmaxbuf, nrb128g * 2, lw1, hpart);
    head1bc_kernel<<<1, 640, 0, stream>>>(hpart, lb1, lw2, lb2, out);
}

// Round 15
// 198.614 us; speedup vs baseline: 1.0017x; 1.0017x over previous
//
#include <hip/hip_runtime.h>
#include <hip/hip_bf16.h>
#include <math.h>

#define NEG_SLOPE 0.2f
typedef unsigned short u16;
typedef short bf16x8 __attribute__((ext_vector_type(8)));
typedef float f32x4 __attribute__((ext_vector_type(4)));

__device__ __forceinline__ float bfu2f(u16 u) { return __uint_as_float(((unsigned)u) << 16); }
__device__ __forceinline__ u16 f2bu(float v) { return __bfloat16_as_ushort(__float2bfloat16(v)); }

__device__ __forceinline__ void gload_lds16(const void* g, void* l) {
    __builtin_amdgcn_global_load_lds((const __attribute__((address_space(1))) void*)g,
                                     (__attribute__((address_space(3))) void*)l, 16, 0, 0);
}

// ---------------- prep: init + x->bf16 + LDS-tiled W transposes + ws/wd ----------------
// blocks: [0,c0) init; [c0,c1) x->bf16; [c1,c1+70) 64x64 transposes; then 80 ws/wd blocks
__global__ void prep_kernel(int* deg, int* cursor, int N,
                            const float* __restrict__ x, u16* __restrict__ xb,
                            const float* __restrict__ W1, u16* __restrict__ Wt1,
                            const float* __restrict__ W2, u16* __restrict__ Wt2,
                            const float* __restrict__ W3, u16* __restrict__ Wt3,
                            const float* __restrict__ as2, const float* __restrict__ ad2,
                            const float* __restrict__ as3, const float* __restrict__ ad3,
                            float* __restrict__ ws2, float* __restrict__ wd2,
                            float* __restrict__ ws3, float* __restrict__ wd3,
                            int c0, int c1) {
    __shared__ u16 sm[64][66];
    int bid = blockIdx.x, tid = threadIdx.x;
    if (bid < c0) {
        int i = bid * 256 + tid;
        if (i < N) { deg[i] = 0; cursor[i] = 0; }
    } else if (bid < c1) {
        int i = (bid - c0) * 1024 + tid * 4;
        if (i < N * 128) {
            float4 v = *(const float4*)(x + i);
            ushort4 st;
            st.x = f2bu(v.x); st.y = f2bu(v.y); st.z = f2bu(v.z); st.w = f2bu(v.w);
            *(ushort4*)(xb + i) = st;
        }
    } else if (bid < c1 + 70) {
        int tb = bid - c1;
        const float* W; u16* Wt; int K, F, kt, ft;
        if (tb < 2)      { W = W1; Wt = Wt1; K = 128; F = 64;   kt = tb;           ft = 0; }
        else if (tb < 6) { W = W2; Wt = Wt2; K = 64;  F = 256;  kt = 0;            ft = tb - 2; }
        else             { W = W3; Wt = Wt3; K = 256; F = 1024; kt = (tb - 6) & 3; ft = (tb - 6) >> 2; }
        int ty = tid >> 6, tx = tid & 63;
#pragma unroll
        for (int r = 0; r < 16; ++r) {
            int kl = r * 4 + ty;
            sm[kl][tx] = f2bu(W[(size_t)(kt * 64 + kl) * F + ft * 64 + tx]);
        }
        __syncthreads();
#pragma unroll
        for (int r = 0; r < 16; ++r) {
            int fl = r * 4 + ty;
            Wt[(size_t)(ft * 64 + fl) * K + kt * 64 + tx] = sm[tx][fl];
        }
    } else {
        int wv = ((bid - c1 - 70) * 256 + tid) >> 6;   // 0..319
        int lane = tid & 63;
        const float *W, *va, *vd; float *os, *od; int F, row;
        if (wv < 64) { W = W2; va = as2; vd = ad2; F = 256; row = wv; os = ws2; od = wd2; }
        else if (wv < 320) { W = W3; va = as3; vd = ad3; F = 1024; row = wv - 64; os = ws3; od = wd3; }
        else return;
        const float* wr = W + (size_t)row * F;
        float ss = 0.f, dd = 0.f;
        for (int f = lane; f < F; f += 64) { float wvv = wr[f]; ss += wvv * va[f]; dd += wvv * vd[f]; }
        for (int off = 32; off; off >>= 1) { ss += __shfl_xor(ss, off); dd += __shfl_xor(dd, off); }
        if (lane == 0) { os[row] = ss; od[row] = dd; }
    }
}

// ---------------- CSR build ----------------
__global__ void count_kernel(const int* __restrict__ edst, int E, int N, int* deg) {
    int i = blockIdx.x * blockDim.x + threadIdx.x;
    int total = E + N;
    if (i >= total) return;
    int dn = (i < E) ? edst[i] : (i - E);
    atomicAdd(&deg[dn], 1);
}

__global__ void scan_kernel(const int* __restrict__ deg, int N, int* __restrict__ offsets) {
    __shared__ int part[257];
    int tid = threadIdx.x;
    int chunk = (N + 255) / 256;
    int begin = tid * chunk;
    int fin = begin + chunk; if (fin > N) fin = N; if (begin > N) begin = N;
    int sum = 0;
    for (int i = begin; i < fin; ++i) sum += deg[i];
    part[tid] = sum;
    __syncthreads();
    if (tid == 0) {
        int acc = 0;
        for (int t = 0; t < 256; ++t) { int v = part[t]; part[t] = acc; acc += v; }
        part[256] = acc;
    }
    __syncthreads();
    int acc = part[tid];
    for (int i = begin; i < fin; ++i) { offsets[i] = acc; acc += deg[i]; }
    if (tid == 255) offsets[N] = part[256];
}

__global__ void scatter_kernel(const int* __restrict__ esrc, const int* __restrict__ edst,
                               int E, int N, const int* __restrict__ offsets,
                               int* cursor, int* __restrict__ srcg) {
    int i = blockIdx.x * blockDim.x + threadIdx.x;
    int total = E + N;
    if (i >= total) return;
    int sn, dn;
    if (i < E) { sn = esrc[i]; dn = edst[i]; } else { sn = i - E; dn = i - E; }
    int pos = atomicAdd(&cursor[dn], 1);
    srcg[offsets[dn] + pos] = sn;
}

// ---------------- register-direct MFMA GEMM (layers 1,2) ----------------
template <int K, int MR, bool BIASRELU, bool SD_EPI>
__global__ __launch_bounds__(256) void mfma_gemm(const u16* __restrict__ A,
                                                 const u16* __restrict__ Wt,
                                                 u16* __restrict__ C,
                                                 const float* __restrict__ bias,
                                                 int M, int F,
                                                 const float* __restrict__ asv,
                                                 const float* __restrict__ adv,
                                                 float* __restrict__ s_out,
                                                 float* __restrict__ d_out) {
    constexpr int NK = K / 32;
    int tid = threadIdx.x;
    int w = tid >> 6, l = tid & 63;
    int l15 = l & 15, q = l >> 4;
    int bm = blockIdx.x * (64 * MR);
    int bn = blockIdx.y * 64;
    int r0 = bm + w * (16 * MR);

    const u16* aptr[MR];
    int row[MR];
#pragma unroll
    for (int mr = 0; mr < MR; ++mr) {
        int r = r0 + mr * 16 + l15;
        row[mr] = r;
        int ar = (r < M) ? r : (M - 1);
        aptr[mr] = A + (size_t)ar * K + 8 * q;
    }
    const u16* bptr[4];
#pragma unroll
    for (int nt = 0; nt < 4; ++nt)
        bptr[nt] = Wt + (size_t)(bn + nt * 16 + l15) * K + 8 * q;

    f32x4 acc[MR][4];
#pragma unroll
    for (int mr = 0; mr < MR; ++mr)
#pragma unroll
        for (int nt = 0; nt < 4; ++nt) acc[mr][nt] = (f32x4){0.f, 0.f, 0.f, 0.f};

    bf16x8 a_cur[MR], b_cur[4], a_nxt[MR], b_nxt[4];
#pragma unroll
    for (int mr = 0; mr < MR; ++mr) a_cur[mr] = *(const bf16x8*)(aptr[mr]);
#pragma unroll
    for (int nt = 0; nt < 4; ++nt) b_cur[nt] = *(const bf16x8*)(bptr[nt]);

#pragma unroll
    for (int kk = 0; kk < NK; ++kk) {
        if (kk + 1 < NK) {
            int koff = (kk + 1) * 32;
#pragma unroll
            for (int mr = 0; mr < MR; ++mr) a_nxt[mr] = *(const bf16x8*)(aptr[mr] + koff);
#pragma unroll
            for (int nt = 0; nt < 4; ++nt) b_nxt[nt] = *(const bf16x8*)(bptr[nt] + koff);
        }
#pragma unroll
        for (int mr = 0; mr < MR; ++mr)
#pragma unroll
            for (int nt = 0; nt < 4; ++nt)
                acc[mr][nt] = __builtin_amdgcn_mfma_f32_16x16x32_bf16(b_cur[nt], a_cur[mr], acc[mr][nt], 0, 0, 0);
        if (kk + 1 < NK) {
#pragma unroll
            for (int mr = 0; mr < MR; ++mr) a_cur[mr] = a_nxt[mr];
#pragma unroll
            for (int nt = 0; nt < 4; ++nt) b_cur[nt] = b_nxt[nt];
        }
    }

#pragma unroll
    for (int mr = 0; mr < MR; ++mr) {
        if (row[mr] >= M) continue;
#pragma unroll
        for (int nt = 0; nt < 4; ++nt) {
            int col = bn + nt * 16 + 4 * q;
            ushort4 st;
#pragma unroll
            for (int r = 0; r < 4; ++r) {
                float v = acc[mr][nt][r];
                if (BIASRELU) { v += bias[col + r]; v = fmaxf(v, 0.f); }
                ((u16*)&st)[r] = f2bu(v);
            }
            *(ushort4*)(C + (size_t)row[mr] * F + col) = st;
        }
    }

    if constexpr (SD_EPI) { // MR==1, grid.y==1, F==64
        float ss = 0.f, dd = 0.f;
#pragma unroll
        for (int nt = 0; nt < 4; ++nt)
#pragma unroll
            for (int r = 0; r < 4; ++r) {
                int col = nt * 16 + 4 * q + r;
                float v = acc[0][nt][r];
                ss += v * asv[col];
                dd += v * adv[col];
            }
        ss += __shfl_xor(ss, 16); ss += __shfl_xor(ss, 32);
        dd += __shfl_xor(dd, 16); dd += __shfl_xor(dd, 32);
        if (q == 0 && row[0] < M) { s_out[row[0]] = ss; d_out[row[0]] = dd; }
    }
}

// ---------------- gemm3: one-shot LDS A + cb-pair loop (B restaged), pool partials ----------------
__global__ __launch_bounds__(512) void gemm3_kernel(const u16* __restrict__ A,
                                                    const u16* __restrict__ Wt,
                                                    const float* __restrict__ bias,
                                                    int M,
                                                    float* __restrict__ pmaxbuf) {
    constexpr int K = 256;
    constexpr int ABYTES = 128 * 512;        // 64 KB
    __shared__ char lds[2 * ABYTES];         // A + B = 128 KB
    int tid = threadIdx.x;
    int w = tid >> 6, lane = tid & 63;
    int w2 = w >> 2, wc = w & 3;             // row-half, col-quarter
    int l15 = lane & 15, q = lane >> 4;
    int bid = blockIdx.x;
    int rb = bid >> 2, cbp = bid & 3;
    int bm = rb * 128;

    // stage A once: 4096 x 16B chunks, swizzled global source
#pragma unroll
    for (int it = 0; it < 8; ++it) {
        int c = it * 512 + tid;
        int row = c >> 5, kc = c & 31;
        int arow = bm + row; if (arow >= M) arow = M - 1;
        gload_lds16(A + (size_t)arow * K + ((kc ^ (row & 7)) * 8),
                    lds + (size_t)(it * 512 + (tid & ~63)) * 16);
    }

    const char* abase = lds;
    char* bldst = lds + ABYTES;

    for (int half = 0; half < 2; ++half) {
        if (half) __syncthreads();           // all waves done reading previous B
        int bn = cbp * 256 + half * 128;
#pragma unroll
        for (int it = 0; it < 8; ++it) {
            int c = it * 512 + tid;
            int col = c >> 5, kc = c & 31;
            gload_lds16(Wt + (size_t)(bn + col) * K + ((kc ^ (col & 7)) * 8),
                        bldst + (size_t)(it * 512 + (tid & ~63)) * 16);
        }
        __syncthreads();

        f32x4 acc[4][2];
#pragma unroll
        for (int mr = 0; mr < 4; ++mr)
#pragma unroll
            for (int nt = 0; nt < 2; ++nt) acc[mr][nt] = (f32x4){0.f, 0.f, 0.f, 0.f};

        const char* bbase = bldst;
#pragma unroll
        for (int kk = 0; kk < 8; ++kk) {
            int c = kk * 4 + q;
            bf16x8 af[4], bfr[2];
#pragma unroll
            for (int mr = 0; mr < 4; ++mr) {
                int row = w2 * 64 + mr * 16 + l15;
                af[mr] = *(const bf16x8*)(abase + row * 512 + ((c ^ (row & 7)) * 16));
            }
#pragma unroll
            for (int nt = 0; nt < 2; ++nt) {
                int col = wc * 32 + nt * 16 + l15;
                bfr[nt] = *(const bf16x8*)(bbase + col * 512 + ((c ^ (col & 7)) * 16));
            }
#pragma unroll
            for (int mr = 0; mr < 4; ++mr)
#pragma unroll
                for (int nt = 0; nt < 2; ++nt)
                    acc[mr][nt] = __builtin_amdgcn_mfma_f32_16x16x32_bf16(bfr[nt], af[mr], acc[mr][nt], 0, 0, 0);
        }

        float pmax[2][4];
#pragma unroll
        for (int nt = 0; nt < 2; ++nt)
#pragma unroll
            for (int r = 0; r < 4; ++r) pmax[nt][r] = 0.f;
#pragma unroll
        for (int mr = 0; mr < 4; ++mr) {
            bool valid = (bm + w2 * 64 + mr * 16 + l15) < M;
#pragma unroll
            for (int nt = 0; nt < 2; ++nt)
#pragma unroll
                for (int r = 0; r < 4; ++r) {
                    float v = acc[mr][nt][r] + bias[bn + wc * 32 + nt * 16 + 4 * q + r];
                    v = fmaxf(v, 0.f);
                    if (valid) pmax[nt][r] = fmaxf(pmax[nt][r], v);
                }
        }
#pragma unroll
        for (int nt = 0; nt < 2; ++nt)
#pragma unroll
            for (int r = 0; r < 4; ++r) {
#pragma unroll
                for (int msk = 1; msk < 16; msk <<= 1)
                    pmax[nt][r] = fmaxf(pmax[nt][r], __shfl_xor(pmax[nt][r], msk));
            }
        if (l15 == 0) {
#pragma unroll
            for (int nt = 0; nt < 2; ++nt)
#pragma unroll
                for (int r = 0; r < 4; ++r)
                    pmaxbuf[(size_t)(rb * 2 + w2) * 1024 + bn + wc * 32 + nt * 16 + 4 * q + r] = pmax[nt][r];
        }
    }
}

// ---------------- standalone sd (layer 3: s,d from a2) ----------------
__global__ void sd_kernel(const u16* __restrict__ h, const float* __restrict__ a_s,
                          const float* __restrict__ a_d, int N, int F,
                          float* __restrict__ s, float* __restrict__ d) {
    int wave = (blockIdx.x * blockDim.x + threadIdx.x) >> 6;
    int lane = threadIdx.x & 63;
    if (wave >= N) return;
    const u16* hrow = h + (size_t)wave * F;
    float ss = 0.f, dd = 0.f;
    for (int f = lane * 4; f < F; f += 256) {
        ushort4 u = *reinterpret_cast<const ushort4*>(hrow + f);
        float4 av = *reinterpret_cast<const float4*>(a_s + f);
        float4 dv = *reinterpret_cast<const float4*>(a_d + f);
        float h0 = bfu2f(u.x), h1 = bfu2f(u.y), h2 = bfu2f(u.z), h3 = bfu2f(u.w);
        ss += h0 * av.x + h1 * av.y + h2 * av.z + h3 * av.w;
        dd += h0 * dv.x + h1 * dv.y + h2 * dv.z + h3 * dv.w;
    }
    for (int off = 32; off; off >>= 1) { ss += __shfl_xor(ss, off); dd += __shfl_xor(dd, off); }
    if (lane == 0) { s[wave] = ss; d[wave] = dd; }
}

// ---------------- alpha: normalized softmax weights per edge (wave-per-node, exp-once) ----------------
__global__ void alpha_kernel(const float* __restrict__ sv, const float* __restrict__ dvec,
                             const int* __restrict__ srcg, const int* __restrict__ offsets,
                             int N, float* __restrict__ ag) {
    int n = (blockIdx.x * blockDim.x + threadIdx.x) >> 6;
    int lane = threadIdx.x & 63;
    if (n >= N) return;
    int start = offsets[n], end = offsets[n + 1];
    float dval = dvec[n];
    if (end - start <= 64) {
        int j0 = start + lane;
        float e0 = -INFINITY;
        if (j0 < end) {
            float v = sv[srcg[j0]] + dval;
            e0 = (v >= 0.f) ? v : NEG_SLOPE * v;
        }
        float m = e0;
#pragma unroll
        for (int off = 32; off; off >>= 1) m = fmaxf(m, __shfl_xor(m, off));
        float p = (j0 < end) ? expf(e0 - m) : 0.f;
        float ls = p;
#pragma unroll
        for (int off = 32; off; off >>= 1) ls += __shfl_xor(ls, off);
        if (j0 < end) ag[j0] = p / ls;
    } else {
        float lmax = -INFINITY;
        for (int j = start + lane; j < end; j += 64) {
            float v = sv[srcg[j]] + dval; v = (v >= 0.f) ? v : NEG_SLOPE * v;
            lmax = fmaxf(lmax, v);
        }
#pragma unroll
        for (int off = 32; off; off >>= 1) lmax = fmaxf(lmax, __shfl_xor(lmax, off));
        float ls = 0.f;
        for (int j = start + lane; j < end; j += 64) {
            float v = sv[srcg[j]] + dval; v = (v >= 0.f) ? v : NEG_SLOPE * v;
            ls += expf(v - lmax);
        }
#pragma unroll
        for (int off = 32; off; off >>= 1) ls += __shfl_xor(ls, off);
        float inv = 1.f / ls;
        for (int j = start + lane; j < end; j += 64) {
            float v = sv[srcg[j]] + dval; v = (v >= 0.f) ? v : NEG_SLOPE * v;
            ag[j] = expf(v - lmax) * inv;
        }
    }
}

// ---------------- pure gather: LDS-staged ag/src, 8-edge unrolled, ushort2/lane ----------------
template <int F, int FS>   // F=256, FS=2 -> FB=128, VPT=2
__global__ __launch_bounds__(256) void gather_kernel(const u16* __restrict__ h,
                                                     const float* __restrict__ ag,
                                                     const int* __restrict__ srcg,
                                                     const int* __restrict__ offsets,
                                                     u16* __restrict__ out) {
    constexpr int FB = F / FS;
    constexpr int VPT = FB / 64;  // 2
    __shared__ float aL[256];
    __shared__ int sL[256];
    __shared__ float red[3][FB];
    int n = blockIdx.x;
    int f0 = blockIdx.y * FB;
    int tid = threadIdx.x, w = tid >> 6, lane = tid & 63;
    int start = offsets[n], end = offsets[n + 1];
    int deg = end - start;
    float acc0 = 0.f, acc1 = 0.f;

    for (int base = 0; base < deg; base += 256) {
        int cnt = deg - base; if (cnt > 256) cnt = 256;
        if (base) __syncthreads();
        if (tid < cnt) { aL[tid] = ag[start + base + tid]; sL[tid] = srcg[start + base + tid]; }
        __syncthreads();
        int j = w;
        for (; j + 28 < cnt; j += 32) {   // 8 independent edges per wave-step
            float a0 = aL[j],      a1 = aL[j + 4],  a2 = aL[j + 8],  a3 = aL[j + 12];
            float a4 = aL[j + 16], a5 = aL[j + 20], a6 = aL[j + 24], a7 = aL[j + 28];
            ushort2 u0 = *(const ushort2*)(h + (size_t)sL[j] * F + f0 + lane * VPT);
            ushort2 u1 = *(const ushort2*)(h + (size_t)sL[j + 4] * F + f0 + lane * VPT);
            ushort2 u2 = *(const ushort2*)(h + (size_t)sL[j + 8] * F + f0 + lane * VPT);
            ushort2 u3 = *(const ushort2*)(h + (size_t)sL[j + 12] * F + f0 + lane * VPT);
            ushort2 u4 = *(const ushort2*)(h + (size_t)sL[j + 16] * F + f0 + lane * VPT);
            ushort2 u5 = *(const ushort2*)(h + (size_t)sL[j + 20] * F + f0 + lane * VPT);
            ushort2 u6 = *(const ushort2*)(h + (size_t)sL[j + 24] * F + f0 + lane * VPT);
            ushort2 u7 = *(const ushort2*)(h + (size_t)sL[j + 28] * F + f0 + lane * VPT);
            acc0 += a0 * bfu2f(u0.x) + a1 * bfu2f(u1.x) + a2 * bfu2f(u2.x) + a3 * bfu2f(u3.x)
                  + a4 * bfu2f(u4.x) + a5 * bfu2f(u5.x) + a6 * bfu2f(u6.x) + a7 * bfu2f(u7.x);
            acc1 += a0 * bfu2f(u0.y) + a1 * bfu2f(u1.y) + a2 * bfu2f(u2.y) + a3 * bfu2f(u3.y)
                  + a4 * bfu2f(u4.y) + a5 * bfu2f(u5.y) + a6 * bfu2f(u6.y) + a7 * bfu2f(u7.y);
        }
        for (; j < cnt; j += 4) {
            float a = aL[j];
            ushort2 u = *(const ushort2*)(h + (size_t)sL[j] * F + f0 + lane * VPT);
            acc0 += a * bfu2f(u.x);
            acc1 += a * bfu2f(u.y);
        }
    }

    if (w > 0) { red[w - 1][lane * 2] = acc0; red[w - 1][lane * 2 + 1] = acc1; }
    __syncthreads();
    if (w != 0) return;
    ushort2 st;
    float x0 = acc0 + red[0][lane * 2] + red[1][lane * 2] + red[2][lane * 2];
    float x1 = acc1 + red[0][lane * 2 + 1] + red[1][lane * 2 + 1] + red[2][lane * 2 + 1];
    st.x = f2bu(x0); st.y = f2bu(x1);
    *(ushort2*)(out + (size_t)n * F + f0 + lane * 2) = st;
}

// ---------------- fused softmax + gather, exp-once LDS softmax (layers 1/2, F=64) ----------------
template <int F, bool BIASRELU, bool SD_EPI>
__global__ __launch_bounds__(256) void agg_kernel(const u16* __restrict__ h,
                                                  const float* __restrict__ sv,
                                                  const float* __restrict__ dvec,
                                                  const int* __restrict__ srcg,
                                                  const int* __restrict__ offsets,
                                                  const float* __restrict__ bias,
                                                  u16* __restrict__ out,
                                                  const float* __restrict__ wsv,
                                                  const float* __restrict__ wdv,
                                                  float* __restrict__ s_out,
                                                  float* __restrict__ d_out) {
    constexpr int VPT = F / 64;
    __shared__ float pL[256];
    __shared__ int sL[256];
    __shared__ float red[3][F];
    int n = blockIdx.x;
    int tid = threadIdx.x;
    int w = tid >> 6, lane = tid & 63;
    int start = offsets[n], end = offsets[n + 1];
    int deg = end - start;
    float dval = dvec[n];
    float acc[VPT];
#pragma unroll
    for (int v = 0; v < VPT; ++v) acc[v] = 0.f;
    float inv;

    auto gpoint = [&](int sn) { return h + (size_t)sn * F + lane * VPT; };
    auto accum = [&](float pw, const u16* hp) {
        if constexpr (VPT == 1) {
            acc[0] += pw * bfu2f(*hp);
        } else {
            ushort2 u = *(const ushort2*)hp;
            acc[0] += pw * bfu2f(u.x); acc[1] += pw * bfu2f(u.y);
        }
    };

    if (deg <= 256) {
        float e = -INFINITY;
        if (tid < deg) {
            int sn = srcg[start + tid];
            sL[tid] = sn;
            float v = sv[sn] + dval;
            e = (v >= 0.f) ? v : NEG_SLOPE * v;
        }
        pL[tid] = e;
        __syncthreads();
        float m = fmaxf(fmaxf(pL[lane], pL[lane + 64]), fmaxf(pL[lane + 128], pL[lane + 192]));
#pragma unroll
        for (int off2 = 32; off2; off2 >>= 1) m = fmaxf(m, __shfl_xor(m, off2));
        __syncthreads();
        float p = (tid < deg) ? expf(e - m) : 0.f;
        pL[tid] = p;
        __syncthreads();
        float t4 = (pL[lane] + pL[lane + 64]) + (pL[lane + 128] + pL[lane + 192]);
#pragma unroll
        for (int off2 = 32; off2; off2 >>= 1) t4 += __shfl_xor(t4, off2);
        inv = 1.f / t4;
        int jj = w;
        for (; jj + 28 < deg; jj += 32) {  // 8 independent edges
            accum(pL[jj], gpoint(sL[jj]));
            accum(pL[jj + 4], gpoint(sL[jj + 4]));
            accum(pL[jj + 8], gpoint(sL[jj + 8]));
            accum(pL[jj + 12], gpoint(sL[jj + 12]));
            accum(pL[jj + 16], gpoint(sL[jj + 16]));
            accum(pL[jj + 20], gpoint(sL[jj + 20]));
            accum(pL[jj + 24], gpoint(sL[jj + 24]));
            accum(pL[jj + 28], gpoint(sL[jj + 28]));
        }
        for (; jj < deg; jj += 4) accum(pL[jj], gpoint(sL[jj]));
    } else {
        float lmax = -INFINITY;
        for (int j = start + lane; j < end; j += 64) {
            float v = sv[srcg[j]] + dval; v = (v >= 0.f) ? v : NEG_SLOPE * v;
            lmax = fmaxf(lmax, v);
        }
#pragma unroll
        for (int off2 = 32; off2; off2 >>= 1) lmax = fmaxf(lmax, __shfl_xor(lmax, off2));
        float ls = 0.f;
        for (int j = start + lane; j < end; j += 64) {
            float v = sv[srcg[j]] + dval; v = (v >= 0.f) ? v : NEG_SLOPE * v;
            ls += expf(v - lmax);
        }
#pragma unroll
        for (int off2 = 32; off2; off2 >>= 1) ls += __shfl_xor(ls, off2);
        inv = 1.f / ls;
        for (int j = start + w; j < end; j += 4) {
            int sn = srcg[j];
            float e2 = sv[sn] + dval; e2 = (e2 >= 0.f) ? e2 : NEG_SLOPE * e2;
            accum(expf(e2 - lmax), gpoint(sn));
        }
    }

    if (w > 0) {
#pragma unroll
        for (int v = 0; v < VPT; ++v) red[w - 1][lane * VPT + v] = acc[v];
    }
    __syncthreads();
    if (w != 0) return;
    float res0 = 0.f;
    if constexpr (VPT == 1) {
        float xv = (acc[0] + red[0][lane] + red[1][lane] + red[2][lane]) * inv;
        if (BIASRELU) { xv += bias[lane]; xv = fmaxf(xv, 0.f); }
        res0 = xv;
        out[(size_t)n * F + lane] = f2bu(xv);
    } else {
        ushort2 st;
#pragma unroll
        for (int v = 0; v < VPT; ++v) {
            float xv = (acc[v] + red[0][lane * 2 + v] + red[1][lane * 2 + v] + red[2][lane * 2 + v]) * inv;
            if (BIASRELU) { xv += bias[lane * 2 + v]; xv = fmaxf(xv, 0.f); }
            ((u16*)&st)[v] = f2bu(xv);
        }
        *(ushort2*)(out + (size_t)n * F + lane * 2) = st;
    }
    if constexpr (SD_EPI) { // F==64
        float ss = res0 * wsv[lane], dd = res0 * wdv[lane];
        for (int off2 = 32; off2; off2 >>= 1) { ss += __shfl_xor(ss, off2); dd += __shfl_xor(dd, off2); }
        if (lane == 0) { s_out[n] = ss; d_out[n] = dd; }
    }
}

// ---------------- dense head (pool fused into head1a) ----------------
__global__ void head1ap_kernel(const float* __restrict__ pmaxbuf, int nslices,
                               const float* __restrict__ lw1, float* __restrict__ part) {
    __shared__ float pk[64];
    int tid = threadIdx.x;          // 128
    int k0 = blockIdx.y * 64;
    if (tid < 64) {
        float m = 0.f;
#pragma unroll 4
        for (int s = 0; s < nslices; ++s) m = fmaxf(m, pmaxbuf[(size_t)s * 1024 + k0 + tid]);
        pk[tid] = m;
    }
    __syncthreads();
    int j = blockIdx.x * 128 + tid;
    float acc = 0.f;
#pragma unroll 8
    for (int kk = 0; kk < 64; ++kk) acc += pk[kk] * lw1[(size_t)(k0 + kk) * 512 + j];
    part[blockIdx.y * 512 + j] = acc;
}

__global__ void head1bc_kernel(const float* __restrict__ part, const float* __restrict__ lb1,
                               const float* __restrict__ lw2, const float* __restrict__ lb2,
                               float* __restrict__ out) {
    __shared__ float zs[512];
    __shared__ float z2s[10];
    int tid = threadIdx.x; // 640 threads = 10 waves
    if (tid < 512) {
        float acc = lb1[tid];
#pragma unroll
        for (int t = 0; t < 16; ++t) acc += part[t * 512 + tid];
        zs[tid] = fmaxf(acc, 0.f);
    }
    __syncthreads();
    int w = tid >> 6, lane = tid & 63;
    if (w < 10) {
        float acc = 0.f;
#pragma unroll
        for (int kc = 0; kc < 8; ++kc) {
            int k = kc * 64 + lane;
            acc += zs[k] * lw2[k * 10 + w];
        }
        for (int off = 32; off; off >>= 1) acc += __shfl_xor(acc, off);
        if (lane == 0) z2s[w] = acc + lb2[w];
    }
    __syncthreads();
    if (tid == 0) {
        float m = z2s[0];
        for (int j = 1; j < 10; ++j) m = fmaxf(m, z2s[j]);
        float ssum = 0.f;
        for (int j = 0; j < 10; ++j) ssum += expf(z2s[j] - m);
        float lse = m + logf(ssum);
        for (int j = 0; j < 10; ++j) out[j] = z2s[j] - lse;
    }
}

extern "C" void kernel_launch(void* const* d_in, const int* in_sizes, int n_in,
                              void* d_out, int out_size, void* d_ws, size_t ws_size,
                              hipStream_t stream) {
    const float* x   = (const float*)d_in[0];
    const int* ei    = (const int*)d_in[1];
    const float* W1  = (const float*)d_in[3];
    const float* as1 = (const float*)d_in[4];
    const float* ad1 = (const float*)d_in[5];
    const float* b1  = (const float*)d_in[6];
    const float* W2  = (const float*)d_in[7];
    const float* as2 = (const float*)d_in[8];
    const float* ad2 = (const float*)d_in[9];
    const float* b2  = (const float*)d_in[10];
    const float* W3  = (const float*)d_in[11];
    const float* as3 = (const float*)d_in[12];
    const float* ad3 = (const float*)d_in[13];
    const float* b3  = (const float*)d_in[14];
    const float* lw1 = (const float*)d_in[15];
    const float* lb1 = (const float*)d_in[16];
    const float* lw2 = (const float*)d_in[17];
    const float* lb2 = (const float*)d_in[18];
    float* out = (float*)d_out;

    const int N = in_sizes[0] / 128;
    const int E = in_sizes[1] / 2;
    const int total = E + N;
    const int* esrc = ei;
    const int* edst = ei + E;

    // bump allocator on d_ws, 256B aligned
    char* base = (char*)d_ws;
    size_t off = 0;
    auto alloc = [&](size_t bytes) { void* p = base + off; off = (off + bytes + 255) & ~(size_t)255; return p; };
    u16* xb    = (u16*)alloc((size_t)N * 128 * 2);
    u16* h1    = (u16*)alloc((size_t)N * 64 * 2);
    u16* a1    = (u16*)alloc((size_t)N * 64 * 2);
    u16* agg2b = (u16*)alloc((size_t)N * 64 * 2);
    u16* a2    = (u16*)alloc((size_t)N * 256 * 2);
    u16* agg3b = (u16*)alloc((size_t)N * 256 * 2);
    u16* Wt1   = (u16*)alloc(128 * 64 * 2);
    u16* Wt2   = (u16*)alloc(64 * 256 * 2);
    u16* Wt3   = (u16*)alloc(256 * 1024 * 2);
    float* ws2 = (float*)alloc(64 * 4);
    float* wd2 = (float*)alloc(64 * 4);
    float* ws3 = (float*)alloc(256 * 4);
    float* wd3 = (float*)alloc(256 * 4);
    float* sbuf = (float*)alloc((size_t)N * 4);
    float* dbuf = (float*)alloc((size_t)N * 4);
    float* ag   = (float*)alloc((size_t)total * 4);
    float* hpart  = (float*)alloc(16 * 512 * 4);
    int* deg     = (int*)alloc((size_t)N * 4);
    int* cursor  = (int*)alloc((size_t)N * 4);
    int* offsets = (int*)alloc((size_t)(N + 1) * 4);
    int* srcg    = (int*)alloc((size_t)total * 4);
    int nrb128g = (N + 127) / 128;
    float* pmaxbuf = (float*)alloc((size_t)nrb128g * 2 * 1024 * 4);

    const int TPB = 256;
    int gE = (total + TPB - 1) / TPB;
    int gW = (N + 3) / 4;
    int gR64 = (N + 63) / 64;
    int gR128 = (N + 127) / 128;

    // prep (init + x->bf16 + tiled W transposes + ws)
    int c0 = (N + 255) / 256;
    int c1 = c0 + (N * 128 + 1023) / 1024;   // x->bf16, 4 elems/thread
    int gP = c1 + 70 + 80;
    prep_kernel<<<gP, TPB, 0, stream>>>(deg, cursor, N, x, xb,
                                        W1, Wt1, W2, Wt2, W3, Wt3,
                                        as2, ad2, as3, ad3, ws2, wd2, ws3, wd3,
                                        c0, c1);

    // CSR build
    count_kernel<<<gE, TPB, 0, stream>>>(edst, E, N, deg);
    scan_kernel<<<1, TPB, 0, stream>>>(deg, N, offsets);
    scatter_kernel<<<gE, TPB, 0, stream>>>(esrc, edst, E, N, offsets, cursor, srcg);

    // ---- layer 1: gemm 64x64 on bf16 xb (+s1,d1 epilogue), fused agg (+s2,d2 epi) ----
    mfma_gemm<128, 1, false, true><<<dim3(gR64, 1), TPB, 0, stream>>>(
        xb, Wt1, h1, nullptr, N, 64, as1, ad1, sbuf, dbuf);
    agg_kernel<64, true, true><<<N, TPB, 0, stream>>>(
        h1, sbuf, dbuf, srcg, offsets, b1, a1, ws2, wd2, sbuf, dbuf);

    // ---- layer 2: fused agg on a1 -> gemm2 (bias+relu) -> a2 ----
    agg_kernel<64, false, false><<<N, TPB, 0, stream>>>(
        a1, sbuf, dbuf, srcg, offsets, nullptr, agg2b, nullptr, nullptr, nullptr, nullptr);
    mfma_gemm<64, 2, true, false><<<dim3(gR128, 4), TPB, 0, stream>>>(
        agg2b, Wt2, a2, b2, N, 256, nullptr, nullptr, nullptr, nullptr);

    // ---- layer 3: sd3 -> alpha (exp-once) -> staged gather (f-split x2) -> gemm3 ----
    sd_kernel<<<gW, TPB, 0, stream>>>(a2, ws3, wd3, N, 256, sbuf, dbuf);
    alpha_kernel<<<gW, TPB, 0, stream>>>(sbuf, dbuf, srcg, offsets, N, ag);
    gather_kernel<256, 2><<<dim3(N, 2), TPB, 0, stream>>>(a2, ag, srcg, offsets, agg3b);
    gemm3_kernel<<<nrb128g * 4, 512, 0, stream>>>(agg3b, Wt3, b3, N, pmaxbuf);

    // ---- head (pool fused into head1ap) ----
    head1ap_kernel<<<dim3(4, 16), 128, 0, stream>>>(pmaxbuf, nrb128g * 2, lw1, hpart);
    head1bc_kernel<<<1, 640, 0, stream>>>(hpart, lb1, lw2, lb2, out);
}

// Round 16
// 187.388 us; speedup vs baseline: 1.0617x; 1.0599x over previous
//
#include <hip/hip_runtime.h>
#include <hip/hip_bf16.h>
#include <math.h>

#define NEG_SLOPE 0.2f
typedef unsigned short u16;
typedef short bf16x8 __attribute__((ext_vector_type(8)));
typedef float f32x4 __attribute__((ext_vector_type(4)));

__device__ __forceinline__ float bfu2f(u16 u) { return __uint_as_float(((unsigned)u) << 16); }
__device__ __forceinline__ u16 f2bu(float v) { return __bfloat16_as_ushort(__float2bfloat16(v)); }

__device__ __forceinline__ void gload_lds16(const void* g, void* l) {
    __builtin_amdgcn_global_load_lds((const __attribute__((address_space(1))) void*)g,
                                     (__attribute__((address_space(3))) void*)l, 16, 0, 0);
}

// ---------------- prep: init + x->bf16 + LDS-tiled W transposes + ws/wd ----------------
__global__ void prep_kernel(int* deg, int* cursor, int N,
                            const float* __restrict__ x, u16* __restrict__ xb,
                            const float* __restrict__ W1, u16* __restrict__ Wt1,
                            const float* __restrict__ W2, u16* __restrict__ Wt2,
                            const float* __restrict__ W3, u16* __restrict__ Wt3,
                            const float* __restrict__ as2, const float* __restrict__ ad2,
                            const float* __restrict__ as3, const float* __restrict__ ad3,
                            float* __restrict__ ws2, float* __restrict__ wd2,
                            float* __restrict__ ws3, float* __restrict__ wd3,
                            int c0, int c1) {
    __shared__ u16 sm[64][66];
    int bid = blockIdx.x, tid = threadIdx.x;
    if (bid < c0) {
        int i = bid * 256 + tid;
        if (i < N) { deg[i] = 0; cursor[i] = 0; }
    } else if (bid < c1) {
        int i = (bid - c0) * 1024 + tid * 4;
        if (i < N * 128) {
            float4 v = *(const float4*)(x + i);
            ushort4 st;
            st.x = f2bu(v.x); st.y = f2bu(v.y); st.z = f2bu(v.z); st.w = f2bu(v.w);
            *(ushort4*)(xb + i) = st;
        }
    } else if (bid < c1 + 70) {
        int tb = bid - c1;
        const float* W; u16* Wt; int K, F, kt, ft;
        if (tb < 2)      { W = W1; Wt = Wt1; K = 128; F = 64;   kt = tb;           ft = 0; }
        else if (tb < 6) { W = W2; Wt = Wt2; K = 64;  F = 256;  kt = 0;            ft = tb - 2; }
        else             { W = W3; Wt = Wt3; K = 256; F = 1024; kt = (tb - 6) & 3; ft = (tb - 6) >> 2; }
        int ty = tid >> 6, tx = tid & 63;
#pragma unroll
        for (int r = 0; r < 16; ++r) {
            int kl = r * 4 + ty;
            sm[kl][tx] = f2bu(W[(size_t)(kt * 64 + kl) * F + ft * 64 + tx]);
        }
        __syncthreads();
#pragma unroll
        for (int r = 0; r < 16; ++r) {
            int fl = r * 4 + ty;
            Wt[(size_t)(ft * 64 + fl) * K + kt * 64 + tx] = sm[tx][fl];
        }
    } else {
        int wv = ((bid - c1 - 70) * 256 + tid) >> 6;   // 0..319
        int lane = tid & 63;
        const float *W, *va, *vd; float *os, *od; int F, row;
        if (wv < 64) { W = W2; va = as2; vd = ad2; F = 256; row = wv; os = ws2; od = wd2; }
        else if (wv < 320) { W = W3; va = as3; vd = ad3; F = 1024; row = wv - 64; os = ws3; od = wd3; }
        else return;
        const float* wr = W + (size_t)row * F;
        float ss = 0.f, dd = 0.f;
        for (int f = lane; f < F; f += 64) { float wvv = wr[f]; ss += wvv * va[f]; dd += wvv * vd[f]; }
        for (int off = 32; off; off >>= 1) { ss += __shfl_xor(ss, off); dd += __shfl_xor(dd, off); }
        if (lane == 0) { os[row] = ss; od[row] = dd; }
    }
}

// ---------------- CSR build ----------------
__global__ void count_kernel(const int* __restrict__ edst, int E, int N, int* deg) {
    int i = blockIdx.x * blockDim.x + threadIdx.x;
    int total = E + N;
    if (i >= total) return;
    int dn = (i < E) ? edst[i] : (i - E);
    atomicAdd(&deg[dn], 1);
}

__global__ void scan_kernel(const int* __restrict__ deg, int N, int* __restrict__ offsets) {
    __shared__ int part[257];
    int tid = threadIdx.x;
    int chunk = (N + 255) / 256;
    int begin = tid * chunk;
    int fin = begin + chunk; if (fin > N) fin = N; if (begin > N) begin = N;
    int sum = 0;
    for (int i = begin; i < fin; ++i) sum += deg[i];
    part[tid] = sum;
    __syncthreads();
    if (tid == 0) {
        int acc = 0;
        for (int t = 0; t < 256; ++t) { int v = part[t]; part[t] = acc; acc += v; }
        part[256] = acc;
    }
    __syncthreads();
    int acc = part[tid];
    for (int i = begin; i < fin; ++i) { offsets[i] = acc; acc += deg[i]; }
    if (tid == 255) offsets[N] = part[256];
}

__global__ void scatter_kernel(const int* __restrict__ esrc, const int* __restrict__ edst,
                               int E, int N, const int* __restrict__ offsets,
                               int* cursor, int* __restrict__ srcg) {
    int i = blockIdx.x * blockDim.x + threadIdx.x;
    int total = E + N;
    if (i >= total) return;
    int sn, dn;
    if (i < E) { sn = esrc[i]; dn = edst[i]; } else { sn = i - E; dn = i - E; }
    int pos = atomicAdd(&cursor[dn], 1);
    srcg[offsets[dn] + pos] = sn;
}

// ---------------- register-direct MFMA GEMM (layers 1,2) ----------------
template <int K, int MR, bool BIASRELU, bool SD_EPI>
__global__ __launch_bounds__(256) void mfma_gemm(const u16* __restrict__ A,
                                                 const u16* __restrict__ Wt,
                                                 u16* __restrict__ C,
                                                 const float* __restrict__ bias,
                                                 int M, int F,
                                                 const float* __restrict__ asv,
                                                 const float* __restrict__ adv,
                                                 float* __restrict__ s_out,
                                                 float* __restrict__ d_out) {
    constexpr int NK = K / 32;
    int tid = threadIdx.x;
    int w = tid >> 6, l = tid & 63;
    int l15 = l & 15, q = l >> 4;
    int bm = blockIdx.x * (64 * MR);
    int bn = blockIdx.y * 64;
    int r0 = bm + w * (16 * MR);

    const u16* aptr[MR];
    int row[MR];
#pragma unroll
    for (int mr = 0; mr < MR; ++mr) {
        int r = r0 + mr * 16 + l15;
        row[mr] = r;
        int ar = (r < M) ? r : (M - 1);
        aptr[mr] = A + (size_t)ar * K + 8 * q;
    }
    const u16* bptr[4];
#pragma unroll
    for (int nt = 0; nt < 4; ++nt)
        bptr[nt] = Wt + (size_t)(bn + nt * 16 + l15) * K + 8 * q;

    f32x4 acc[MR][4];
#pragma unroll
    for (int mr = 0; mr < MR; ++mr)
#pragma unroll
        for (int nt = 0; nt < 4; ++nt) acc[mr][nt] = (f32x4){0.f, 0.f, 0.f, 0.f};

    bf16x8 a_cur[MR], b_cur[4], a_nxt[MR], b_nxt[4];
#pragma unroll
    for (int mr = 0; mr < MR; ++mr) a_cur[mr] = *(const bf16x8*)(aptr[mr]);
#pragma unroll
    for (int nt = 0; nt < 4; ++nt) b_cur[nt] = *(const bf16x8*)(bptr[nt]);

#pragma unroll
    for (int kk = 0; kk < NK; ++kk) {
        if (kk + 1 < NK) {
            int koff = (kk + 1) * 32;
#pragma unroll
            for (int mr = 0; mr < MR; ++mr) a_nxt[mr] = *(const bf16x8*)(aptr[mr] + koff);
#pragma unroll
            for (int nt = 0; nt < 4; ++nt) b_nxt[nt] = *(const bf16x8*)(bptr[nt] + koff);
        }
#pragma unroll
        for (int mr = 0; mr < MR; ++mr)
#pragma unroll
            for (int nt = 0; nt < 4; ++nt)
                acc[mr][nt] = __builtin_amdgcn_mfma_f32_16x16x32_bf16(b_cur[nt], a_cur[mr], acc[mr][nt], 0, 0, 0);
        if (kk + 1 < NK) {
#pragma unroll
            for (int mr = 0; mr < MR; ++mr) a_cur[mr] = a_nxt[mr];
#pragma unroll
            for (int nt = 0; nt < 4; ++nt) b_cur[nt] = b_nxt[nt];
        }
    }

#pragma unroll
    for (int mr = 0; mr < MR; ++mr) {
        if (row[mr] >= M) continue;
#pragma unroll
        for (int nt = 0; nt < 4; ++nt) {
            int col = bn + nt * 16 + 4 * q;
            ushort4 st;
#pragma unroll
            for (int r = 0; r < 4; ++r) {
                float v = acc[mr][nt][r];
                if (BIASRELU) { v += bias[col + r]; v = fmaxf(v, 0.f); }
                ((u16*)&st)[r] = f2bu(v);
            }
            *(ushort4*)(C + (size_t)row[mr] * F + col) = st;
        }
    }

    if constexpr (SD_EPI) { // MR==1, grid.y==1, F==64
        float ss = 0.f, dd = 0.f;
#pragma unroll
        for (int nt = 0; nt < 4; ++nt)
#pragma unroll
            for (int r = 0; r < 4; ++r) {
                int col = nt * 16 + 4 * q + r;
                float v = acc[0][nt][r];
                ss += v * asv[col];
                dd += v * adv[col];
            }
        ss += __shfl_xor(ss, 16); ss += __shfl_xor(ss, 32);
        dd += __shfl_xor(dd, 16); dd += __shfl_xor(dd, 32);
        if (q == 0 && row[0] < M) { s_out[row[0]] = ss; d_out[row[0]] = dd; }
    }
}

// ---------------- gemm3: one-shot LDS A + cb-pair loop (B restaged), pool partials ----------------
__global__ __launch_bounds__(512) void gemm3_kernel(const u16* __restrict__ A,
                                                    const u16* __restrict__ Wt,
                                                    const float* __restrict__ bias,
                                                    int M,
                                                    float* __restrict__ pmaxbuf) {
    constexpr int K = 256;
    constexpr int ABYTES = 128 * 512;        // 64 KB
    __shared__ char lds[2 * ABYTES];         // A + B = 128 KB
    int tid = threadIdx.x;
    int w = tid >> 6, lane = tid & 63;
    int w2 = w >> 2, wc = w & 3;             // row-half, col-quarter
    int l15 = lane & 15, q = lane >> 4;
    int bid = blockIdx.x;
    int rb = bid >> 2, cbp = bid & 3;
    int bm = rb * 128;

    // stage A once: 4096 x 16B chunks, swizzled global source
#pragma unroll
    for (int it = 0; it < 8; ++it) {
        int c = it * 512 + tid;
        int row = c >> 5, kc = c & 31;
        int arow = bm + row; if (arow >= M) arow = M - 1;
        gload_lds16(A + (size_t)arow * K + ((kc ^ (row & 7)) * 8),
                    lds + (size_t)(it * 512 + (tid & ~63)) * 16);
    }

    const char* abase = lds;
    char* bldst = lds + ABYTES;

    for (int half = 0; half < 2; ++half) {
        if (half) __syncthreads();           // all waves done reading previous B
        int bn = cbp * 256 + half * 128;
#pragma unroll
        for (int it = 0; it < 8; ++it) {
            int c = it * 512 + tid;
            int col = c >> 5, kc = c & 31;
            gload_lds16(Wt + (size_t)(bn + col) * K + ((kc ^ (col & 7)) * 8),
                        bldst + (size_t)(it * 512 + (tid & ~63)) * 16);
        }
        __syncthreads();

        f32x4 acc[4][2];
#pragma unroll
        for (int mr = 0; mr < 4; ++mr)
#pragma unroll
            for (int nt = 0; nt < 2; ++nt) acc[mr][nt] = (f32x4){0.f, 0.f, 0.f, 0.f};

        const char* bbase = bldst;
#pragma unroll
        for (int kk = 0; kk < 8; ++kk) {
            int c = kk * 4 + q;
            bf16x8 af[4], bfr[2];
#pragma unroll
            for (int mr = 0; mr < 4; ++mr) {
                int row = w2 * 64 + mr * 16 + l15;
                af[mr] = *(const bf16x8*)(abase + row * 512 + ((c ^ (row & 7)) * 16));
            }
#pragma unroll
            for (int nt = 0; nt < 2; ++nt) {
                int col = wc * 32 + nt * 16 + l15;
                bfr[nt] = *(const bf16x8*)(bbase + col * 512 + ((c ^ (col & 7)) * 16));
            }
#pragma unroll
            for (int mr = 0; mr < 4; ++mr)
#pragma unroll
                for (int nt = 0; nt < 2; ++nt)
                    acc[mr][nt] = __builtin_amdgcn_mfma_f32_16x16x32_bf16(bfr[nt], af[mr], acc[mr][nt], 0, 0, 0);
        }

        float pmax[2][4];
#pragma unroll
        for (int nt = 0; nt < 2; ++nt)
#pragma unroll
            for (int r = 0; r < 4; ++r) pmax[nt][r] = 0.f;
#pragma unroll
        for (int mr = 0; mr < 4; ++mr) {
            bool valid = (bm + w2 * 64 + mr * 16 + l15) < M;
#pragma unroll
            for (int nt = 0; nt < 2; ++nt)
#pragma unroll
                for (int r = 0; r < 4; ++r) {
                    float v = acc[mr][nt][r] + bias[bn + wc * 32 + nt * 16 + 4 * q + r];
                    v = fmaxf(v, 0.f);
                    if (valid) pmax[nt][r] = fmaxf(pmax[nt][r], v);
                }
        }
#pragma unroll
        for (int nt = 0; nt < 2; ++nt)
#pragma unroll
            for (int r = 0; r < 4; ++r) {
#pragma unroll
                for (int msk = 1; msk < 16; msk <<= 1)
                    pmax[nt][r] = fmaxf(pmax[nt][r], __shfl_xor(pmax[nt][r], msk));
            }
        if (l15 == 0) {
#pragma unroll
            for (int nt = 0; nt < 2; ++nt)
#pragma unroll
                for (int r = 0; r < 4; ++r)
                    pmaxbuf[(size_t)(rb * 2 + w2) * 1024 + bn + wc * 32 + nt * 16 + 4 * q + r] = pmax[nt][r];
        }
    }
}

// ---------------- standalone sd (layer 3: s,d from a2) ----------------
__global__ void sd_kernel(const u16* __restrict__ h, const float* __restrict__ a_s,
                          const float* __restrict__ a_d, int N, int F,
                          float* __restrict__ s, float* __restrict__ d) {
    int wave = (blockIdx.x * blockDim.x + threadIdx.x) >> 6;
    int lane = threadIdx.x & 63;
    if (wave >= N) return;
    const u16* hrow = h + (size_t)wave * F;
    float ss = 0.f, dd = 0.f;
    for (int f = lane * 4; f < F; f += 256) {
        ushort4 u = *reinterpret_cast<const ushort4*>(hrow + f);
        float4 av = *reinterpret_cast<const float4*>(a_s + f);
        float4 dv = *reinterpret_cast<const float4*>(a_d + f);
        float h0 = bfu2f(u.x), h1 = bfu2f(u.y), h2 = bfu2f(u.z), h3 = bfu2f(u.w);
        ss += h0 * av.x + h1 * av.y + h2 * av.z + h3 * av.w;
        dd += h0 * dv.x + h1 * dv.y + h2 * dv.z + h3 * dv.w;
    }
    for (int off = 32; off; off >>= 1) { ss += __shfl_xor(ss, off); dd += __shfl_xor(dd, off); }
    if (lane == 0) { s[wave] = ss; d[wave] = dd; }
}

// ---------------- alpha: normalized softmax weights per edge (wave-per-node, exp-once) ----------------
__global__ void alpha_kernel(const float* __restrict__ sv, const float* __restrict__ dvec,
                             const int* __restrict__ srcg, const int* __restrict__ offsets,
                             int N, float* __restrict__ ag) {
    int n = (blockIdx.x * blockDim.x + threadIdx.x) >> 6;
    int lane = threadIdx.x & 63;
    if (n >= N) return;
    int start = offsets[n], end = offsets[n + 1];
    float dval = dvec[n];
    if (end - start <= 64) {
        int j0 = start + lane;
        float e0 = -INFINITY;
        if (j0 < end) {
            float v = sv[srcg[j0]] + dval;
            e0 = (v >= 0.f) ? v : NEG_SLOPE * v;
        }
        float m = e0;
#pragma unroll
        for (int off = 32; off; off >>= 1) m = fmaxf(m, __shfl_xor(m, off));
        float p = (j0 < end) ? expf(e0 - m) : 0.f;
        float ls = p;
#pragma unroll
        for (int off = 32; off; off >>= 1) ls += __shfl_xor(ls, off);
        if (j0 < end) ag[j0] = p / ls;
    } else {
        float lmax = -INFINITY;
        for (int j = start + lane; j < end; j += 64) {
            float v = sv[srcg[j]] + dval; v = (v >= 0.f) ? v : NEG_SLOPE * v;
            lmax = fmaxf(lmax, v);
        }
#pragma unroll
        for (int off = 32; off; off >>= 1) lmax = fmaxf(lmax, __shfl_xor(lmax, off));
        float ls = 0.f;
        for (int j = start + lane; j < end; j += 64) {
            float v = sv[srcg[j]] + dval; v = (v >= 0.f) ? v : NEG_SLOPE * v;
            ls += expf(v - lmax);
        }
#pragma unroll
        for (int off = 32; off; off >>= 1) ls += __shfl_xor(ls, off);
        float inv = 1.f / ls;
        for (int j = start + lane; j < end; j += 64) {
            float v = sv[srcg[j]] + dval; v = (v >= 0.f) ? v : NEG_SLOPE * v;
            ag[j] = expf(v - lmax) * inv;
        }
    }
}

// ---------------- pure gather: LDS-staged ag/src, 4-edge unrolled, ushort2/lane ----------------
template <int F, int FS>   // F=256, FS=2 -> FB=128, VPT=2
__global__ __launch_bounds__(256) void gather_kernel(const u16* __restrict__ h,
                                                     const float* __restrict__ ag,
                                                     const int* __restrict__ srcg,
                                                     const int* __restrict__ offsets,
                                                     u16* __restrict__ out) {
    constexpr int FB = F / FS;
    constexpr int VPT = FB / 64;  // 2
    __shared__ float aL[256];
    __shared__ int sL[256];
    __shared__ float red[3][FB];
    int n = blockIdx.x;
    int f0 = blockIdx.y * FB;
    int tid = threadIdx.x, w = tid >> 6, lane = tid & 63;
    int start = offsets[n], end = offsets[n + 1];
    int deg = end - start;
    float acc0 = 0.f, acc1 = 0.f;

    for (int base = 0; base < deg; base += 256) {
        int cnt = deg - base; if (cnt > 256) cnt = 256;
        if (base) __syncthreads();
        if (tid < cnt) { aL[tid] = ag[start + base + tid]; sL[tid] = srcg[start + base + tid]; }
        __syncthreads();
        int j = w;
        for (; j + 12 < cnt; j += 16) {   // 4 independent edges per wave-step
            float a0 = aL[j], a1 = aL[j + 4], a2 = aL[j + 8], a3 = aL[j + 12];
            ushort2 u0 = *(const ushort2*)(h + (size_t)sL[j] * F + f0 + lane * VPT);
            ushort2 u1 = *(const ushort2*)(h + (size_t)sL[j + 4] * F + f0 + lane * VPT);
            ushort2 u2 = *(const ushort2*)(h + (size_t)sL[j + 8] * F + f0 + lane * VPT);
            ushort2 u3 = *(const ushort2*)(h + (size_t)sL[j + 12] * F + f0 + lane * VPT);
            acc0 += a0 * bfu2f(u0.x) + a1 * bfu2f(u1.x) + a2 * bfu2f(u2.x) + a3 * bfu2f(u3.x);
            acc1 += a0 * bfu2f(u0.y) + a1 * bfu2f(u1.y) + a2 * bfu2f(u2.y) + a3 * bfu2f(u3.y);
        }
        for (; j < cnt; j += 4) {
            float a = aL[j];
            ushort2 u = *(const ushort2*)(h + (size_t)sL[j] * F + f0 + lane * VPT);
            acc0 += a * bfu2f(u.x);
            acc1 += a * bfu2f(u.y);
        }
    }

    if (w > 0) { red[w - 1][lane * 2] = acc0; red[w - 1][lane * 2 + 1] = acc1; }
    __syncthreads();
    if (w != 0) return;
    ushort2 st;
    float x0 = acc0 + red[0][lane * 2] + red[1][lane * 2] + red[2][lane * 2];
    float x1 = acc1 + red[0][lane * 2 + 1] + red[1][lane * 2 + 1] + red[2][lane * 2 + 1];
    st.x = f2bu(x0); st.y = f2bu(x1);
    *(ushort2*)(out + (size_t)n * F + f0 + lane * 2) = st;
}

// ---------------- fused softmax + gather, exp-once LDS softmax (layers 1/2, F=64) ----------------
template <int F, bool BIASRELU, bool SD_EPI>
__global__ __launch_bounds__(256) void agg_kernel(const u16* __restrict__ h,
                                                  const float* __restrict__ sv,
                                                  const float* __restrict__ dvec,
                                                  const int* __restrict__ srcg,
                                                  const int* __restrict__ offsets,
                                                  const float* __restrict__ bias,
                                                  u16* __restrict__ out,
                                                  const float* __restrict__ wsv,
                                                  const float* __restrict__ wdv,
                                                  float* __restrict__ s_out,
                                                  float* __restrict__ d_out) {
    constexpr int VPT = F / 64;
    __shared__ float pL[256];
    __shared__ int sL[256];
    __shared__ float red[3][F];
    int n = blockIdx.x;
    int tid = threadIdx.x;
    int w = tid >> 6, lane = tid & 63;
    int start = offsets[n], end = offsets[n + 1];
    int deg = end - start;
    float dval = dvec[n];
    float acc[VPT];
#pragma unroll
    for (int v = 0; v < VPT; ++v) acc[v] = 0.f;
    float inv;

    auto gpoint = [&](int sn) { return h + (size_t)sn * F + lane * VPT; };
    auto accum = [&](float pw, const u16* hp) {
        if constexpr (VPT == 1) {
            acc[0] += pw * bfu2f(*hp);
        } else {
            ushort2 u = *(const ushort2*)hp;
            acc[0] += pw * bfu2f(u.x); acc[1] += pw * bfu2f(u.y);
        }
    };

    if (deg <= 256) {
        float e = -INFINITY;
        if (tid < deg) {
            int sn = srcg[start + tid];
            sL[tid] = sn;
            float v = sv[sn] + dval;
            e = (v >= 0.f) ? v : NEG_SLOPE * v;
        }
        pL[tid] = e;
        __syncthreads();
        float m = fmaxf(fmaxf(pL[lane], pL[lane + 64]), fmaxf(pL[lane + 128], pL[lane + 192]));
#pragma unroll
        for (int off2 = 32; off2; off2 >>= 1) m = fmaxf(m, __shfl_xor(m, off2));
        __syncthreads();
        float p = (tid < deg) ? expf(e - m) : 0.f;
        pL[tid] = p;
        __syncthreads();
        float t4 = (pL[lane] + pL[lane + 64]) + (pL[lane + 128] + pL[lane + 192]);
#pragma unroll
        for (int off2 = 32; off2; off2 >>= 1) t4 += __shfl_xor(t4, off2);
        inv = 1.f / t4;
        int jj = w;
        for (; jj + 12 < deg; jj += 16) {  // 4 independent edges
            accum(pL[jj], gpoint(sL[jj]));
            accum(pL[jj + 4], gpoint(sL[jj + 4]));
            accum(pL[jj + 8], gpoint(sL[jj + 8]));
            accum(pL[jj + 12], gpoint(sL[jj + 12]));
        }
        for (; jj < deg; jj += 4) accum(pL[jj], gpoint(sL[jj]));
    } else {
        float lmax = -INFINITY;
        for (int j = start + lane; j < end; j += 64) {
            float v = sv[srcg[j]] + dval; v = (v >= 0.f) ? v : NEG_SLOPE * v;
            lmax = fmaxf(lmax, v);
        }
#pragma unroll
        for (int off2 = 32; off2; off2 >>= 1) lmax = fmaxf(lmax, __shfl_xor(lmax, off2));
        float ls = 0.f;
        for (int j = start + lane; j < end; j += 64) {
            float v = sv[srcg[j]] + dval; v = (v >= 0.f) ? v : NEG_SLOPE * v;
            ls += expf(v - lmax);
        }
#pragma unroll
        for (int off2 = 32; off2; off2 >>= 1) ls += __shfl_xor(ls, off2);
        inv = 1.f / ls;
        for (int j = start + w; j < end; j += 4) {
            int sn = srcg[j];
            float e2 = sv[sn] + dval; e2 = (e2 >= 0.f) ? e2 : NEG_SLOPE * e2;
            accum(expf(e2 - lmax), gpoint(sn));
        }
    }

    if (w > 0) {
#pragma unroll
        for (int v = 0; v < VPT; ++v) red[w - 1][lane * VPT + v] = acc[v];
    }
    __syncthreads();
    if (w != 0) return;
    float res0 = 0.f;
    if constexpr (VPT == 1) {
        float xv = (acc[0] + red[0][lane] + red[1][lane] + red[2][lane]) * inv;
        if (BIASRELU) { xv += bias[lane]; xv = fmaxf(xv, 0.f); }
        res0 = xv;
        out[(size_t)n * F + lane] = f2bu(xv);
    } else {
        ushort2 st;
#pragma unroll
        for (int v = 0; v < VPT; ++v) {
            float xv = (acc[v] + red[0][lane * 2 + v] + red[1][lane * 2 + v] + red[2][lane * 2 + v]) * inv;
            if (BIASRELU) { xv += bias[lane * 2 + v]; xv = fmaxf(xv, 0.f); }
            ((u16*)&st)[v] = f2bu(xv);
        }
        *(ushort2*)(out + (size_t)n * F + lane * 2) = st;
    }
    if constexpr (SD_EPI) { // F==64
        float ss = res0 * wsv[lane], dd = res0 * wdv[lane];
        for (int off2 = 32; off2; off2 >>= 1) { ss += __shfl_xor(ss, off2); dd += __shfl_xor(dd, off2); }
        if (lane == 0) { s_out[n] = ss; d_out[n] = dd; }
    }
}

// ---------------- dense head (pool fused into head1a) ----------------
__global__ void head1ap_kernel(const float* __restrict__ pmaxbuf, int nslices,
                               const float* __restrict__ lw1, float* __restrict__ part) {
    __shared__ float pk[64];
    int tid = threadIdx.x;          // 128
    int k0 = blockIdx.y * 64;
    if (tid < 64) {
        float m = 0.f;
#pragma unroll 4
        for (int s = 0; s < nslices; ++s) m = fmaxf(m, pmaxbuf[(size_t)s * 1024 + k0 + tid]);
        pk[tid] = m;
    }
    __syncthreads();
    int j = blockIdx.x * 128 + tid;
    float acc = 0.f;
#pragma unroll 8
    for (int kk = 0; kk < 64; ++kk) acc += pk[kk] * lw1[(size_t)(k0 + kk) * 512 + j];
    part[blockIdx.y * 512 + j] = acc;
}

__global__ void head1bc_kernel(const float* __restrict__ part, const float* __restrict__ lb1,
                               const float* __restrict__ lw2, const float* __restrict__ lb2,
                               float* __restrict__ out) {
    __shared__ float zs[512];
    __shared__ float z2s[10];
    int tid = threadIdx.x; // 640 threads = 10 waves
    if (tid < 512) {
        float acc = lb1[tid];
#pragma unroll
        for (int t = 0; t < 16; ++t) acc += part[t * 512 + tid];
        zs[tid] = fmaxf(acc, 0.f);
    }
    __syncthreads();
    int w = tid >> 6, lane = tid & 63;
    if (w < 10) {
        float acc = 0.f;
#pragma unroll
        for (int kc = 0; kc < 8; ++kc) {
            int k = kc * 64 + lane;
            acc += zs[k] * lw2[k * 10 + w];
        }
        for (int off = 32; off; off >>= 1) acc += __shfl_xor(acc, off);
        if (lane == 0) z2s[w] = acc + lb2[w];
    }
    __syncthreads();
    if (tid == 0) {
        float m = z2s[0];
        for (int j = 1; j < 10; ++j) m = fmaxf(m, z2s[j]);
        float ssum = 0.f;
        for (int j = 0; j < 10; ++j) ssum += expf(z2s[j] - m);
        float lse = m + logf(ssum);
        for (int j = 0; j < 10; ++j) out[j] = z2s[j] - lse;
    }
}

extern "C" void kernel_launch(void* const* d_in, const int* in_sizes, int n_in,
                              void* d_out, int out_size, void* d_ws, size_t ws_size,
                              hipStream_t stream) {
    const float* x   = (const float*)d_in[0];
    const int* ei    = (const int*)d_in[1];
    const float* W1  = (const float*)d_in[3];
    const float* as1 = (const float*)d_in[4];
    const float* ad1 = (const float*)d_in[5];
    const float* b1  = (const float*)d_in[6];
    const float* W2  = (const float*)d_in[7];
    const float* as2 = (const float*)d_in[8];
    const float* ad2 = (const float*)d_in[9];
    const float* b2  = (const float*)d_in[10];
    const float* W3  = (const float*)d_in[11];
    const float* as3 = (const float*)d_in[12];
    const float* ad3 = (const float*)d_in[13];
    const float* b3  = (const float*)d_in[14];
    const float* lw1 = (const float*)d_in[15];
    const float* lb1 = (const float*)d_in[16];
    const float* lw2 = (const float*)d_in[17];
    const float* lb2 = (const float*)d_in[18];
    float* out = (float*)d_out;

    const int N = in_sizes[0] / 128;
    const int E = in_sizes[1] / 2;
    const int total = E + N;
    const int* esrc = ei;
    const int* edst = ei + E;

    // bump allocator on d_ws, 256B aligned
    char* base = (char*)d_ws;
    size_t off = 0;
    auto alloc = [&](size_t bytes) { void* p = base + off; off = (off + bytes + 255) & ~(size_t)255; return p; };
    u16* xb    = (u16*)alloc((size_t)N * 128 * 2);
    u16* h1    = (u16*)alloc((size_t)N * 64 * 2);
    u16* a1    = (u16*)alloc((size_t)N * 64 * 2);
    u16* agg2b = (u16*)alloc((size_t)N * 64 * 2);
    u16* a2    = (u16*)alloc((size_t)N * 256 * 2);
    u16* agg3b = (u16*)alloc((size_t)N * 256 * 2);
    u16* Wt1   = (u16*)alloc(128 * 64 * 2);
    u16* Wt2   = (u16*)alloc(64 * 256 * 2);
    u16* Wt3   = (u16*)alloc(256 * 1024 * 2);
    float* ws2 = (float*)alloc(64 * 4);
    float* wd2 = (float*)alloc(64 * 4);
    float* ws3 = (float*)alloc(256 * 4);
    float* wd3 = (float*)alloc(256 * 4);
    float* sbuf = (float*)alloc((size_t)N * 4);
    float* dbuf = (float*)alloc((size_t)N * 4);
    float* ag   = (float*)alloc((size_t)total * 4);
    float* hpart  = (float*)alloc(16 * 512 * 4);
    int* deg     = (int*)alloc((size_t)N * 4);
    int* cursor  = (int*)alloc((size_t)N * 4);
    int* offsets = (int*)alloc((size_t)(N + 1) * 4);
    int* srcg    = (int*)alloc((size_t)total * 4);
    int nrb128g = (N + 127) / 128;
    float* pmaxbuf = (float*)alloc((size_t)nrb128g * 2 * 1024 * 4);

    const int TPB = 256;
    int gE = (total + TPB - 1) / TPB;
    int gW = (N + 3) / 4;
    int gR64 = (N + 63) / 64;
    int gR128 = (N + 127) / 128;

    // prep (init + x->bf16 + tiled W transposes + ws)
    int c0 = (N + 255) / 256;
    int c1 = c0 + (N * 128 + 1023) / 1024;
    int gP = c1 + 70 + 80;
    prep_kernel<<<gP, TPB, 0, stream>>>(deg, cursor, N, x, xb,
                                        W1, Wt1, W2, Wt2, W3, Wt3,
                                        as2, ad2, as3, ad3, ws2, wd2, ws3, wd3,
                                        c0, c1);

    // CSR build
    count_kernel<<<gE, TPB, 0, stream>>>(edst, E, N, deg);
    scan_kernel<<<1, TPB, 0, stream>>>(deg, N, offsets);
    scatter_kernel<<<gE, TPB, 0, stream>>>(esrc, edst, E, N, offsets, cursor, srcg);

    // ---- layer 1: gemm 64x64 on bf16 xb (+s1,d1 epilogue), fused agg (+s2,d2 epi) ----
    mfma_gemm<128, 1, false, true><<<dim3(gR64, 1), TPB, 0, stream>>>(
        xb, Wt1, h1, nullptr, N, 64, as1, ad1, sbuf, dbuf);
    agg_kernel<64, true, true><<<N, TPB, 0, stream>>>(
        h1, sbuf, dbuf, srcg, offsets, b1, a1, ws2, wd2, sbuf, dbuf);

    // ---- layer 2: fused agg on a1 -> gemm2 (bias+relu) -> a2 ----
    agg_kernel<64, false, false><<<N, TPB, 0, stream>>>(
        a1, sbuf, dbuf, srcg, offsets, nullptr, agg2b, nullptr, nullptr, nullptr, nullptr);
    mfma_gemm<64, 2, true, false><<<dim3(gR128, 4), TPB, 0, stream>>>(
        agg2b, Wt2, a2, b2, N, 256, nullptr, nullptr, nullptr, nullptr);

    // ---- layer 3: sd3 -> alpha (exp-once) -> staged gather (f-split x2) -> gemm3 ----
    sd_kernel<<<gW, TPB, 0, stream>>>(a2, ws3, wd3, N, 256, sbuf, dbuf);
    alpha_kernel<<<gW, TPB, 0, stream>>>(sbuf, dbuf, srcg, offsets, N, ag);
    gather_kernel<256, 2><<<dim3(N, 2), TPB, 0, stream>>>(a2, ag, srcg, offsets, agg3b);
    gemm3_kernel<<<nrb128g * 4, 512, 0, stream>>>(agg3b, Wt3, b3, N, pmaxbuf);

    // ---- head (pool fused into head1ap) ----
    head1ap_kernel<<<dim3(4, 16), 128, 0, stream>>>(pmaxbuf, nrb128g * 2, lw1, hpart);
    head1bc_kernel<<<1, 640, 0, stream>>>(hpart, lb1, lw2, lb2, out);
}

// Round 17
// 179.098 us; speedup vs baseline: 1.1109x; 1.0463x over previous
//
#include <hip/hip_runtime.h>
#include <hip/hip_bf16.h>
#include <math.h>

#define NEG_SLOPE 0.2f
typedef unsigned short u16;
typedef short bf16x8 __attribute__((ext_vector_type(8)));
typedef float f32x4 __attribute__((ext_vector_type(4)));

__device__ __forceinline__ float bfu2f(u16 u) { return __uint_as_float(((unsigned)u) << 16); }
__device__ __forceinline__ u16 f2bu(float v) { return __bfloat16_as_ushort(__float2bfloat16(v)); }

__device__ __forceinline__ void gload_lds16(const void* g, void* l) {
    __builtin_amdgcn_global_load_lds((const __attribute__((address_space(1))) void*)g,
                                     (__attribute__((address_space(3))) void*)l, 16, 0, 0);
}

// ---------------- prep: init + x->bf16 + LDS-tiled W transposes + ws/wd ----------------
__global__ void prep_kernel(int* deg, int* cursor, int N,
                            const float* __restrict__ x, u16* __restrict__ xb,
                            const float* __restrict__ W1, u16* __restrict__ Wt1,
                            const float* __restrict__ W2, u16* __restrict__ Wt2,
                            const float* __restrict__ W3, u16* __restrict__ Wt3,
                            const float* __restrict__ as2, const float* __restrict__ ad2,
                            const float* __restrict__ as3, const float* __restrict__ ad3,
                            float* __restrict__ ws2, float* __restrict__ wd2,
                            float* __restrict__ ws3, float* __restrict__ wd3,
                            int c0, int c1) {
    __shared__ u16 sm[64][66];
    int bid = blockIdx.x, tid = threadIdx.x;
    if (bid < c0) {
        int i = bid * 256 + tid;
        if (i < N) { deg[i] = 0; cursor[i] = 0; }
    } else if (bid < c1) {
        int i = (bid - c0) * 1024 + tid * 4;
        if (i < N * 128) {
            float4 v = *(const float4*)(x + i);
            ushort4 st;
            st.x = f2bu(v.x); st.y = f2bu(v.y); st.z = f2bu(v.z); st.w = f2bu(v.w);
            *(ushort4*)(xb + i) = st;
        }
    } else if (bid < c1 + 70) {
        int tb = bid - c1;
        const float* W; u16* Wt; int K, F, kt, ft;
        if (tb < 2)      { W = W1; Wt = Wt1; K = 128; F = 64;   kt = tb;           ft = 0; }
        else if (tb < 6) { W = W2; Wt = Wt2; K = 64;  F = 256;  kt = 0;            ft = tb - 2; }
        else             { W = W3; Wt = Wt3; K = 256; F = 1024; kt = (tb - 6) & 3; ft = (tb - 6) >> 2; }
        int ty = tid >> 6, tx = tid & 63;
#pragma unroll
        for (int r = 0; r < 16; ++r) {
            int kl = r * 4 + ty;
            sm[kl][tx] = f2bu(W[(size_t)(kt * 64 + kl) * F + ft * 64 + tx]);
        }
        __syncthreads();
#pragma unroll
        for (int r = 0; r < 16; ++r) {
            int fl = r * 4 + ty;
            Wt[(size_t)(ft * 64 + fl) * K + kt * 64 + tx] = sm[tx][fl];
        }
    } else {
        int wv = ((bid - c1 - 70) * 256 + tid) >> 6;   // 0..319
        int lane = tid & 63;
        const float *W, *va, *vd; float *os, *od; int F, row;
        if (wv < 64) { W = W2; va = as2; vd = ad2; F = 256; row = wv; os = ws2; od = wd2; }
        else if (wv < 320) { W = W3; va = as3; vd = ad3; F = 1024; row = wv - 64; os = ws3; od = wd3; }
        else return;
        const float* wr = W + (size_t)row * F;
        float ss = 0.f, dd = 0.f;
        for (int f = lane; f < F; f += 64) { float wvv = wr[f]; ss += wvv * va[f]; dd += wvv * vd[f]; }
        for (int off = 32; off; off >>= 1) { ss += __shfl_xor(ss, off); dd += __shfl_xor(dd, off); }
        if (lane == 0) { os[row] = ss; od[row] = dd; }
    }
}

// ---------------- CSR build ----------------
__global__ void count_kernel(const int* __restrict__ edst, int E, int N, int* deg) {
    int i = blockIdx.x * blockDim.x + threadIdx.x;
    int total = E + N;
    if (i >= total) return;
    int dn = (i < E) ? edst[i] : (i - E);
    atomicAdd(&deg[dn], 1);
}

__global__ void scan_kernel(const int* __restrict__ deg, int N, int* __restrict__ offsets) {
    __shared__ int part[257];
    int tid = threadIdx.x;
    int chunk = (N + 255) / 256;
    int begin = tid * chunk;
    int fin = begin + chunk; if (fin > N) fin = N; if (begin > N) begin = N;
    int sum = 0;
    for (int i = begin; i < fin; ++i) sum += deg[i];
    part[tid] = sum;
    __syncthreads();
    if (tid == 0) {
        int acc = 0;
        for (int t = 0; t < 256; ++t) { int v = part[t]; part[t] = acc; acc += v; }
        part[256] = acc;
    }
    __syncthreads();
    int acc = part[tid];
    for (int i = begin; i < fin; ++i) { offsets[i] = acc; acc += deg[i]; }
    if (tid == 255) offsets[N] = part[256];
}

__global__ void scatter_kernel(const int* __restrict__ esrc, const int* __restrict__ edst,
                               int E, int N, const int* __restrict__ offsets,
                               int* cursor, int* __restrict__ srcg) {
    int i = blockIdx.x * blockDim.x + threadIdx.x;
    int total = E + N;
    if (i >= total) return;
    int sn, dn;
    if (i < E) { sn = esrc[i]; dn = edst[i]; } else { sn = i - E; dn = i - E; }
    int pos = atomicAdd(&cursor[dn], 1);
    srcg[offsets[dn] + pos] = sn;
}

// ---------------- register-direct MFMA GEMM (layers 1,2) ----------------
template <int K, int MR, bool BIASRELU, bool SD_EPI>
__global__ __launch_bounds__(256) void mfma_gemm(const u16* __restrict__ A,
                                                 const u16* __restrict__ Wt,
                                                 u16* __restrict__ C,
                                                 const float* __restrict__ bias,
                                                 int M, int F,
                                                 const float* __restrict__ asv,
                                                 const float* __restrict__ adv,
                                                 float* __restrict__ s_out,
                                                 float* __restrict__ d_out) {
    constexpr int NK = K / 32;
    int tid = threadIdx.x;
    int w = tid >> 6, l = tid & 63;
    int l15 = l & 15, q = l >> 4;
    int bm = blockIdx.x * (64 * MR);
    int bn = blockIdx.y * 64;
    int r0 = bm + w * (16 * MR);

    const u16* aptr[MR];
    int row[MR];
#pragma unroll
    for (int mr = 0; mr < MR; ++mr) {
        int r = r0 + mr * 16 + l15;
        row[mr] = r;
        int ar = (r < M) ? r : (M - 1);
        aptr[mr] = A + (size_t)ar * K + 8 * q;
    }
    const u16* bptr[4];
#pragma unroll
    for (int nt = 0; nt < 4; ++nt)
        bptr[nt] = Wt + (size_t)(bn + nt * 16 + l15) * K + 8 * q;

    f32x4 acc[MR][4];
#pragma unroll
    for (int mr = 0; mr < MR; ++mr)
#pragma unroll
        for (int nt = 0; nt < 4; ++nt) acc[mr][nt] = (f32x4){0.f, 0.f, 0.f, 0.f};

    bf16x8 a_cur[MR], b_cur[4], a_nxt[MR], b_nxt[4];
#pragma unroll
    for (int mr = 0; mr < MR; ++mr) a_cur[mr] = *(const bf16x8*)(aptr[mr]);
#pragma unroll
    for (int nt = 0; nt < 4; ++nt) b_cur[nt] = *(const bf16x8*)(bptr[nt]);

#pragma unroll
    for (int kk = 0; kk < NK; ++kk) {
        if (kk + 1 < NK) {
            int koff = (kk + 1) * 32;
#pragma unroll
            for (int mr = 0; mr < MR; ++mr) a_nxt[mr] = *(const bf16x8*)(aptr[mr] + koff);
#pragma unroll
            for (int nt = 0; nt < 4; ++nt) b_nxt[nt] = *(const bf16x8*)(bptr[nt] + koff);
        }
#pragma unroll
        for (int mr = 0; mr < MR; ++mr)
#pragma unroll
            for (int nt = 0; nt < 4; ++nt)
                acc[mr][nt] = __builtin_amdgcn_mfma_f32_16x16x32_bf16(b_cur[nt], a_cur[mr], acc[mr][nt], 0, 0, 0);
        if (kk + 1 < NK) {
#pragma unroll
            for (int mr = 0; mr < MR; ++mr) a_cur[mr] = a_nxt[mr];
#pragma unroll
            for (int nt = 0; nt < 4; ++nt) b_cur[nt] = b_nxt[nt];
        }
    }

#pragma unroll
    for (int mr = 0; mr < MR; ++mr) {
        if (row[mr] >= M) continue;
#pragma unroll
        for (int nt = 0; nt < 4; ++nt) {
            int col = bn + nt * 16 + 4 * q;
            ushort4 st;
#pragma unroll
            for (int r = 0; r < 4; ++r) {
                float v = acc[mr][nt][r];
                if (BIASRELU) { v += bias[col + r]; v = fmaxf(v, 0.f); }
                ((u16*)&st)[r] = f2bu(v);
            }
            *(ushort4*)(C + (size_t)row[mr] * F + col) = st;
        }
    }

    if constexpr (SD_EPI) { // MR==1, grid.y==1, F==64
        float ss = 0.f, dd = 0.f;
#pragma unroll
        for (int nt = 0; nt < 4; ++nt)
#pragma unroll
            for (int r = 0; r < 4; ++r) {
                int col = nt * 16 + 4 * q + r;
                float v = acc[0][nt][r];
                ss += v * asv[col];
                dd += v * adv[col];
            }
        ss += __shfl_xor(ss, 16); ss += __shfl_xor(ss, 32);
        dd += __shfl_xor(dd, 16); dd += __shfl_xor(dd, 32);
        if (q == 0 && row[0] < M) { s_out[row[0]] = ss; d_out[row[0]] = dd; }
    }
}

// ---------------- gemm3: LDS A + cb-pair loop, XCD-grouped blocks, pool partials ----------------
// grid 320 blocks; lid = (bid&7)*40 + (bid>>3) groups the 4 cbp of each rb (and 10 rb)
// on one XCD so the A-tiles stay L2-resident.
__global__ __launch_bounds__(512) void gemm3_kernel(const u16* __restrict__ A,
                                                    const u16* __restrict__ Wt,
                                                    const float* __restrict__ bias,
                                                    int M, int nlid,
                                                    float* __restrict__ pmaxbuf) {
    constexpr int K = 256;
    constexpr int ABYTES = 128 * 512;        // 64 KB
    __shared__ char lds[2 * ABYTES];         // A + B = 128 KB
    int tid = threadIdx.x;
    int w = tid >> 6, lane = tid & 63;
    int w2 = w >> 2, wc = w & 3;             // row-half, col-quarter
    int l15 = lane & 15, q = lane >> 4;
    int bid = blockIdx.x;
    int lid = (bid & 7) * 40 + (bid >> 3);
    if (lid >= nlid) return;
    int rb = lid >> 2, cbp = lid & 3;
    int bm = rb * 128;

    // stage A once: 4096 x 16B chunks, swizzled global source
#pragma unroll
    for (int it = 0; it < 8; ++it) {
        int c = it * 512 + tid;
        int row = c >> 5, kc = c & 31;
        int arow = bm + row; if (arow >= M) arow = M - 1;
        gload_lds16(A + (size_t)arow * K + ((kc ^ (row & 7)) * 8),
                    lds + (size_t)(it * 512 + (tid & ~63)) * 16);
    }

    const char* abase = lds;
    char* bldst = lds + ABYTES;

    for (int half = 0; half < 2; ++half) {
        if (half) __syncthreads();           // all waves done reading previous B
        int bn = cbp * 256 + half * 128;
#pragma unroll
        for (int it = 0; it < 8; ++it) {
            int c = it * 512 + tid;
            int col = c >> 5, kc = c & 31;
            gload_lds16(Wt + (size_t)(bn + col) * K + ((kc ^ (col & 7)) * 8),
                        bldst + (size_t)(it * 512 + (tid & ~63)) * 16);
        }
        __syncthreads();

        f32x4 acc[4][2];
#pragma unroll
        for (int mr = 0; mr < 4; ++mr)
#pragma unroll
            for (int nt = 0; nt < 2; ++nt) acc[mr][nt] = (f32x4){0.f, 0.f, 0.f, 0.f};

        const char* bbase = bldst;
#pragma unroll
        for (int kk = 0; kk < 8; ++kk) {
            int c = kk * 4 + q;
            bf16x8 af[4], bfr[2];
#pragma unroll
            for (int mr = 0; mr < 4; ++mr) {
                int row = w2 * 64 + mr * 16 + l15;
                af[mr] = *(const bf16x8*)(abase + row * 512 + ((c ^ (row & 7)) * 16));
            }
#pragma unroll
            for (int nt = 0; nt < 2; ++nt) {
                int col = wc * 32 + nt * 16 + l15;
                bfr[nt] = *(const bf16x8*)(bbase + col * 512 + ((c ^ (col & 7)) * 16));
            }
#pragma unroll
            for (int mr = 0; mr < 4; ++mr)
#pragma unroll
                for (int nt = 0; nt < 2; ++nt)
                    acc[mr][nt] = __builtin_amdgcn_mfma_f32_16x16x32_bf16(bfr[nt], af[mr], acc[mr][nt], 0, 0, 0);
        }

        float pmax[2][4];
#pragma unroll
        for (int nt = 0; nt < 2; ++nt)
#pragma unroll
            for (int r = 0; r < 4; ++r) pmax[nt][r] = 0.f;
#pragma unroll
        for (int mr = 0; mr < 4; ++mr) {
            bool valid = (bm + w2 * 64 + mr * 16 + l15) < M;
#pragma unroll
            for (int nt = 0; nt < 2; ++nt)
#pragma unroll
                for (int r = 0; r < 4; ++r) {
                    float v = acc[mr][nt][r] + bias[bn + wc * 32 + nt * 16 + 4 * q + r];
                    v = fmaxf(v, 0.f);
                    if (valid) pmax[nt][r] = fmaxf(pmax[nt][r], v);
                }
        }
#pragma unroll
        for (int nt = 0; nt < 2; ++nt)
#pragma unroll
            for (int r = 0; r < 4; ++r) {
#pragma unroll
                for (int msk = 1; msk < 16; msk <<= 1)
                    pmax[nt][r] = fmaxf(pmax[nt][r], __shfl_xor(pmax[nt][r], msk));
            }
        if (l15 == 0) {
#pragma unroll
            for (int nt = 0; nt < 2; ++nt)
#pragma unroll
                for (int r = 0; r < 4; ++r)
                    pmaxbuf[(size_t)(rb * 2 + w2) * 1024 + bn + wc * 32 + nt * 16 + 4 * q + r] = pmax[nt][r];
        }
    }
}

// ---------------- standalone sd (layer 3: s,d from a2) ----------------
__global__ void sd_kernel(const u16* __restrict__ h, const float* __restrict__ a_s,
                          const float* __restrict__ a_d, int N, int F,
                          float* __restrict__ s, float* __restrict__ d) {
    int wave = (blockIdx.x * blockDim.x + threadIdx.x) >> 6;
    int lane = threadIdx.x & 63;
    if (wave >= N) return;
    const u16* hrow = h + (size_t)wave * F;
    float ss = 0.f, dd = 0.f;
    for (int f = lane * 4; f < F; f += 256) {
        ushort4 u = *reinterpret_cast<const ushort4*>(hrow + f);
        float4 av = *reinterpret_cast<const float4*>(a_s + f);
        float4 dv = *reinterpret_cast<const float4*>(a_d + f);
        float h0 = bfu2f(u.x), h1 = bfu2f(u.y), h2 = bfu2f(u.z), h3 = bfu2f(u.w);
        ss += h0 * av.x + h1 * av.y + h2 * av.z + h3 * av.w;
        dd += h0 * dv.x + h1 * dv.y + h2 * dv.z + h3 * dv.w;
    }
    for (int off = 32; off; off >>= 1) { ss += __shfl_xor(ss, off); dd += __shfl_xor(dd, off); }
    if (lane == 0) { s[wave] = ss; d[wave] = dd; }
}

// ---------------- alpha: normalized softmax weights per edge (wave-per-node, exp-once) ----------------
__global__ void alpha_kernel(const float* __restrict__ sv, const float* __restrict__ dvec,
                             const int* __restrict__ srcg, const int* __restrict__ offsets,
                             int N, float* __restrict__ ag) {
    int n = (blockIdx.x * blockDim.x + threadIdx.x) >> 6;
    int lane = threadIdx.x & 63;
    if (n >= N) return;
    int start = offsets[n], end = offsets[n + 1];
    float dval = dvec[n];
    if (end - start <= 64) {
        int j0 = start + lane;
        float e0 = -INFINITY;
        if (j0 < end) {
            float v = sv[srcg[j0]] + dval;
            e0 = (v >= 0.f) ? v : NEG_SLOPE * v;
        }
        float m = e0;
#pragma unroll
        for (int off = 32; off; off >>= 1) m = fmaxf(m, __shfl_xor(m, off));
        float p = (j0 < end) ? expf(e0 - m) : 0.f;
        float ls = p;
#pragma unroll
        for (int off = 32; off; off >>= 1) ls += __shfl_xor(ls, off);
        if (j0 < end) ag[j0] = p / ls;
    } else {
        float lmax = -INFINITY;
        for (int j = start + lane; j < end; j += 64) {
            float v = sv[srcg[j]] + dval; v = (v >= 0.f) ? v : NEG_SLOPE * v;
            lmax = fmaxf(lmax, v);
        }
#pragma unroll
        for (int off = 32; off; off >>= 1) lmax = fmaxf(lmax, __shfl_xor(lmax, off));
        float ls = 0.f;
        for (int j = start + lane; j < end; j += 64) {
            float v = sv[srcg[j]] + dval; v = (v >= 0.f) ? v : NEG_SLOPE * v;
            ls += expf(v - lmax);
        }
#pragma unroll
        for (int off = 32; off; off >>= 1) ls += __shfl_xor(ls, off);
        float inv = 1.f / ls;
        for (int j = start + lane; j < end; j += 64) {
            float v = sv[srcg[j]] + dval; v = (v >= 0.f) ? v : NEG_SLOPE * v;
            ag[j] = expf(v - lmax) * inv;
        }
    }
}

// ---------------- pure gather (layer 3): full 512B row per wave (ushort4), 4-edge unrolled ----------------
__global__ __launch_bounds__(256) void gather_kernel(const u16* __restrict__ h,
                                                     const float* __restrict__ ag,
                                                     const int* __restrict__ srcg,
                                                     const int* __restrict__ offsets,
                                                     u16* __restrict__ out) {
    constexpr int F = 256;
    __shared__ float aL[256];
    __shared__ int sL[256];
    __shared__ float red[3][256];
    int n = blockIdx.x;
    int tid = threadIdx.x, w = tid >> 6, lane = tid & 63;
    int start = offsets[n], end = offsets[n + 1];
    int deg = end - start;
    float acc0 = 0.f, acc1 = 0.f, acc2 = 0.f, acc3 = 0.f;
    int fo = lane * 4;

    for (int base = 0; base < deg; base += 256) {
        int cnt = deg - base; if (cnt > 256) cnt = 256;
        if (base) __syncthreads();
        if (tid < cnt) { aL[tid] = ag[start + base + tid]; sL[tid] = srcg[start + base + tid]; }
        __syncthreads();
        int j = w;
        for (; j + 12 < cnt; j += 16) {   // 4 independent full-row reads per wave-step
            float a0 = aL[j], a1 = aL[j + 4], a2 = aL[j + 8], a3 = aL[j + 12];
            ushort4 u0 = *(const ushort4*)(h + (size_t)sL[j] * F + fo);
            ushort4 u1 = *(const ushort4*)(h + (size_t)sL[j + 4] * F + fo);
            ushort4 u2 = *(const ushort4*)(h + (size_t)sL[j + 8] * F + fo);
            ushort4 u3 = *(const ushort4*)(h + (size_t)sL[j + 12] * F + fo);
            acc0 += a0 * bfu2f(u0.x) + a1 * bfu2f(u1.x) + a2 * bfu2f(u2.x) + a3 * bfu2f(u3.x);
            acc1 += a0 * bfu2f(u0.y) + a1 * bfu2f(u1.y) + a2 * bfu2f(u2.y) + a3 * bfu2f(u3.y);
            acc2 += a0 * bfu2f(u0.z) + a1 * bfu2f(u1.z) + a2 * bfu2f(u2.z) + a3 * bfu2f(u3.z);
            acc3 += a0 * bfu2f(u0.w) + a1 * bfu2f(u1.w) + a2 * bfu2f(u2.w) + a3 * bfu2f(u3.w);
        }
        for (; j < cnt; j += 4) {
            float a = aL[j];
            ushort4 u = *(const ushort4*)(h + (size_t)sL[j] * F + fo);
            acc0 += a * bfu2f(u.x);
            acc1 += a * bfu2f(u.y);
            acc2 += a * bfu2f(u.z);
            acc3 += a * bfu2f(u.w);
        }
    }

    if (w > 0) {
        red[w - 1][fo] = acc0; red[w - 1][fo + 1] = acc1;
        red[w - 1][fo + 2] = acc2; red[w - 1][fo + 3] = acc3;
    }
    __syncthreads();
    if (w != 0) return;
    ushort4 st;
    st.x = f2bu(acc0 + red[0][fo] + red[1][fo] + red[2][fo]);
    st.y = f2bu(acc1 + red[0][fo + 1] + red[1][fo + 1] + red[2][fo + 1]);
    st.z = f2bu(acc2 + red[0][fo + 2] + red[1][fo + 2] + red[2][fo + 2]);
    st.w = f2bu(acc3 + red[0][fo + 3] + red[1][fo + 3] + red[2][fo + 3]);
    *(ushort4*)(out + (size_t)n * F + fo) = st;
}

// ---------------- fused softmax + gather, exp-once LDS softmax (layers 1/2, F=64) ----------------
template <int F, bool BIASRELU, bool SD_EPI>
__global__ __launch_bounds__(256) void agg_kernel(const u16* __restrict__ h,
                                                  const float* __restrict__ sv,
                                                  const float* __restrict__ dvec,
                                                  const int* __restrict__ srcg,
                                                  const int* __restrict__ offsets,
                                                  const float* __restrict__ bias,
                                                  u16* __restrict__ out,
                                                  const float* __restrict__ wsv,
                                                  const float* __restrict__ wdv,
                                                  float* __restrict__ s_out,
                                                  float* __restrict__ d_out) {
    constexpr int VPT = F / 64;
    __shared__ float pL[256];
    __shared__ int sL[256];
    __shared__ float red[3][F];
    int n = blockIdx.x;
    int tid = threadIdx.x;
    int w = tid >> 6, lane = tid & 63;
    int start = offsets[n], end = offsets[n + 1];
    int deg = end - start;
    float dval = dvec[n];
    float acc[VPT];
#pragma unroll
    for (int v = 0; v < VPT; ++v) acc[v] = 0.f;
    float inv;

    auto gpoint = [&](int sn) { return h + (size_t)sn * F + lane * VPT; };
    auto accum = [&](float pw, const u16* hp) {
        if constexpr (VPT == 1) {
            acc[0] += pw * bfu2f(*hp);
        } else {
            ushort2 u = *(const ushort2*)hp;
            acc[0] += pw * bfu2f(u.x); acc[1] += pw * bfu2f(u.y);
        }
    };

    if (deg <= 256) {
        float e = -INFINITY;
        if (tid < deg) {
            int sn = srcg[start + tid];
            sL[tid] = sn;
            float v = sv[sn] + dval;
            e = (v >= 0.f) ? v : NEG_SLOPE * v;
        }
        pL[tid] = e;
        __syncthreads();
        float m = fmaxf(fmaxf(pL[lane], pL[lane + 64]), fmaxf(pL[lane + 128], pL[lane + 192]));
#pragma unroll
        for (int off2 = 32; off2; off2 >>= 1) m = fmaxf(m, __shfl_xor(m, off2));
        __syncthreads();
        float p = (tid < deg) ? expf(e - m) : 0.f;
        pL[tid] = p;
        __syncthreads();
        float t4 = (pL[lane] + pL[lane + 64]) + (pL[lane + 128] + pL[lane + 192]);
#pragma unroll
        for (int off2 = 32; off2; off2 >>= 1) t4 += __shfl_xor(t4, off2);
        inv = 1.f / t4;
        int jj = w;
        for (; jj + 12 < deg; jj += 16) {  // 4 independent edges
            accum(pL[jj], gpoint(sL[jj]));
            accum(pL[jj + 4], gpoint(sL[jj + 4]));
            accum(pL[jj + 8], gpoint(sL[jj + 8]));
            accum(pL[jj + 12], gpoint(sL[jj + 12]));
        }
        for (; jj < deg; jj += 4) accum(pL[jj], gpoint(sL[jj]));
    } else {
        float lmax = -INFINITY;
        for (int j = start + lane; j < end; j += 64) {
            float v = sv[srcg[j]] + dval; v = (v >= 0.f) ? v : NEG_SLOPE * v;
            lmax = fmaxf(lmax, v);
        }
#pragma unroll
        for (int off2 = 32; off2; off2 >>= 1) lmax = fmaxf(lmax, __shfl_xor(lmax, off2));
        float ls = 0.f;
        for (int j = start + lane; j < end; j += 64) {
            float v = sv[srcg[j]] + dval; v = (v >= 0.f) ? v : NEG_SLOPE * v;
            ls += expf(v - lmax);
        }
#pragma unroll
        for (int off2 = 32; off2; off2 >>= 1) ls += __shfl_xor(ls, off2);
        inv = 1.f / ls;
        for (int j = start + w; j < end; j += 4) {
            int sn = srcg[j];
            float e2 = sv[sn] + dval; e2 = (e2 >= 0.f) ? e2 : NEG_SLOPE * e2;
            accum(expf(e2 - lmax), gpoint(sn));
        }
    }

    if (w > 0) {
#pragma unroll
        for (int v = 0; v < VPT; ++v) red[w - 1][lane * VPT + v] = acc[v];
    }
    __syncthreads();
    if (w != 0) return;
    float res0 = 0.f;
    if constexpr (VPT == 1) {
        float xv = (acc[0] + red[0][lane] + red[1][lane] + red[2][lane]) * inv;
        if (BIASRELU) { xv += bias[lane]; xv = fmaxf(xv, 0.f); }
        res0 = xv;
        out[(size_t)n * F + lane] = f2bu(xv);
    } else {
        ushort2 st;
#pragma unroll
        for (int v = 0; v < VPT; ++v) {
            float xv = (acc[v] + red[0][lane * 2 + v] + red[1][lane * 2 + v] + red[2][lane * 2 + v]) * inv;
            if (BIASRELU) { xv += bias[lane * 2 + v]; xv = fmaxf(xv, 0.f); }
            ((u16*)&st)[v] = f2bu(xv);
        }
        *(ushort2*)(out + (size_t)n * F + lane * 2) = st;
    }
    if constexpr (SD_EPI) { // F==64
        float ss = res0 * wsv[lane], dd = res0 * wdv[lane];
        for (int off2 = 32; off2; off2 >>= 1) { ss += __shfl_xor(ss, off2); dd += __shfl_xor(dd, off2); }
        if (lane == 0) { s_out[n] = ss; d_out[n] = dd; }
    }
}

// ---------------- dense head (pool fused into head1a) ----------------
__global__ void head1ap_kernel(const float* __restrict__ pmaxbuf, int nslices,
                               const float* __restrict__ lw1, float* __restrict__ part) {
    __shared__ float pk[64];
    int tid = threadIdx.x;          // 128
    int k0 = blockIdx.y * 64;
    if (tid < 64) {
        float m = 0.f;
#pragma unroll 4
        for (int s = 0; s < nslices; ++s) m = fmaxf(m, pmaxbuf[(size_t)s * 1024 + k0 + tid]);
        pk[tid] = m;
    }
    __syncthreads();
    int j = blockIdx.x * 128 + tid;
    float acc = 0.f;
#pragma unroll 8
    for (int kk = 0; kk < 64; ++kk) acc += pk[kk] * lw1[(size_t)(k0 + kk) * 512 + j];
    part[blockIdx.y * 512 + j] = acc;
}

__global__ void head1bc_kernel(const float* __restrict__ part, const float* __restrict__ lb1,
                               const float* __restrict__ lw2, const float* __restrict__ lb2,
                               float* __restrict__ out) {
    __shared__ float zs[512];
    __shared__ float z2s[10];
    int tid = threadIdx.x; // 640 threads = 10 waves
    if (tid < 512) {
        float acc = lb1[tid];
#pragma unroll
        for (int t = 0; t < 16; ++t) acc += part[t * 512 + tid];
        zs[tid] = fmaxf(acc, 0.f);
    }
    __syncthreads();
    int w = tid >> 6, lane = tid & 63;
    if (w < 10) {
        float acc = 0.f;
#pragma unroll
        for (int kc = 0; kc < 8; ++kc) {
            int k = kc * 64 + lane;
            acc += zs[k] * lw2[k * 10 + w];
        }
        for (int off = 32; off; off >>= 1) acc += __shfl_xor(acc, off);
        if (lane == 0) z2s[w] = acc + lb2[w];
    }
    __syncthreads();
    if (tid == 0) {
        float m = z2s[0];
        for (int j = 1; j < 10; ++j) m = fmaxf(m, z2s[j]);
        float ssum = 0.f;
        for (int j = 0; j < 10; ++j) ssum += expf(z2s[j] - m);
        float lse = m + logf(ssum);
        for (int j = 0; j < 10; ++j) out[j] = z2s[j] - lse;
    }
}

extern "C" void kernel_launch(void* const* d_in, const int* in_sizes, int n_in,
                              void* d_out, int out_size, void* d_ws, size_t ws_size,
                              hipStream_t stream) {
    const float* x   = (const float*)d_in[0];
    const int* ei    = (const int*)d_in[1];
    const float* W1  = (const float*)d_in[3];
    const float* as1 = (const float*)d_in[4];
    const float* ad1 = (const float*)d_in[5];
    const float* b1  = (const float*)d_in[6];
    const float* W2  = (const float*)d_in[7];
    const float* as2 = (const float*)d_in[8];
    const float* ad2 = (const float*)d_in[9];
    const float* b2  = (const float*)d_in[10];
    const float* W3  = (const float*)d_in[11];
    const float* as3 = (const float*)d_in[12];
    const float* ad3 = (const float*)d_in[13];
    const float* b3  = (const float*)d_in[14];
    const float* lw1 = (const float*)d_in[15];
    const float* lb1 = (const float*)d_in[16];
    const float* lw2 = (const float*)d_in[17];
    const float* lb2 = (const float*)d_in[18];
    float* out = (float*)d_out;

    const int N = in_sizes[0] / 128;
    const int E = in_sizes[1] / 2;
    const int total = E + N;
    const int* esrc = ei;
    const int* edst = ei + E;

    // bump allocator on d_ws, 256B aligned
    char* base = (char*)d_ws;
    size_t off = 0;
    auto alloc = [&](size_t bytes) { void* p = base + off; off = (off + bytes + 255) & ~(size_t)255; return p; };
    u16* xb    = (u16*)alloc((size_t)N * 128 * 2);
    u16* h1    = (u16*)alloc((size_t)N * 64 * 2);
    u16* a1    = (u16*)alloc((size_t)N * 64 * 2);
    u16* agg2b = (u16*)alloc((size_t)N * 64 * 2);
    u16* a2    = (u16*)alloc((size_t)N * 256 * 2);
    u16* agg3b = (u16*)alloc((size_t)N * 256 * 2);
    u16* Wt1   = (u16*)alloc(128 * 64 * 2);
    u16* Wt2   = (u16*)alloc(64 * 256 * 2);
    u16* Wt3   = (u16*)alloc(256 * 1024 * 2);
    float* ws2 = (float*)alloc(64 * 4);
    float* wd2 = (float*)alloc(64 * 4);
    float* ws3 = (float*)alloc(256 * 4);
    float* wd3 = (float*)alloc(256 * 4);
    float* sbuf = (float*)alloc((size_t)N * 4);
    float* dbuf = (float*)alloc((size_t)N * 4);
    float* ag   = (float*)alloc((size_t)total * 4);
    float* hpart  = (float*)alloc(16 * 512 * 4);
    int* deg     = (int*)alloc((size_t)N * 4);
    int* cursor  = (int*)alloc((size_t)N * 4);
    int* offsets = (int*)alloc((size_t)(N + 1) * 4);
    int* srcg    = (int*)alloc((size_t)total * 4);
    int nrb128g = (N + 127) / 128;
    float* pmaxbuf = (float*)alloc((size_t)nrb128g * 2 * 1024 * 4);

    const int TPB = 256;
    int gE = (total + TPB - 1) / TPB;
    int gW = (N + 3) / 4;
    int gR64 = (N + 63) / 64;
    int gR128 = (N + 127) / 128;

    // prep (init + x->bf16 + tiled W transposes + ws)
    int c0 = (N + 255) / 256;
    int c1 = c0 + (N * 128 + 1023) / 1024;
    int gP = c1 + 70 + 80;
    prep_kernel<<<gP, TPB, 0, stream>>>(deg, cursor, N, x, xb,
                                        W1, Wt1, W2, Wt2, W3, Wt3,
                                        as2, ad2, as3, ad3, ws2, wd2, ws3, wd3,
                                        c0, c1);

    // CSR build
    count_kernel<<<gE, TPB, 0, stream>>>(edst, E, N, deg);
    scan_kernel<<<1, TPB, 0, stream>>>(deg, N, offsets);
    scatter_kernel<<<gE, TPB, 0, stream>>>(esrc, edst, E, N, offsets, cursor, srcg);

    // ---- layer 1: gemm 64x64 on bf16 xb (+s1,d1 epilogue), fused agg (+s2,d2 epi) ----
    mfma_gemm<128, 1, false, true><<<dim3(gR64, 1), TPB, 0, stream>>>(
        xb, Wt1, h1, nullptr, N, 64, as1, ad1, sbuf, dbuf);
    agg_kernel<64, true, true><<<N, TPB, 0, stream>>>(
        h1, sbuf, dbuf, srcg, offsets, b1, a1, ws2, wd2, sbuf, dbuf);

    // ---- layer 2: fused agg on a1 -> gemm2 (bias+relu) -> a2 ----
    agg_kernel<64, false, false><<<N, TPB, 0, stream>>>(
        a1, sbuf, dbuf, srcg, offsets, nullptr, agg2b, nullptr, nullptr, nullptr, nullptr);
    mfma_gemm<64, 2, true, false><<<dim3(gR128, 4), TPB, 0, stream>>>(
        agg2b, Wt2, a2, b2, N, 256, nullptr, nullptr, nullptr, nullptr);

    // ---- layer 3: sd3 -> alpha (exp-once) -> full-row gather -> gemm3 (XCD-grouped) ----
    sd_kernel<<<gW, TPB, 0, stream>>>(a2, ws3, wd3, N, 256, sbuf, dbuf);
    alpha_kernel<<<gW, TPB, 0, stream>>>(sbuf, dbuf, srcg, offsets, N, ag);
    gather_kernel<<<N, TPB, 0, stream>>>(a2, ag, srcg, offsets, agg3b);
    gemm3_kernel<<<320, 512, 0, stream>>>(agg3b, Wt3, b3, N, nrb128g * 4, pmaxbuf);

    // ---- head (pool fused into head1ap) ----
    head1ap_kernel<<<dim3(4, 16), 128, 0, stream>>>(pmaxbuf, nrb128g * 2, lw1, hpart);
    head1bc_kernel<<<1, 640, 0, stream>>>(hpart, lb1, lw2, lb2, out);
}